// Round 4
// baseline (246.744 us; speedup 1.0000x reference)
//
#include <hip/hip_runtime.h>
#include <hip/hip_bf16.h>
#include <math.h>

// Problem constants
#define BB 2
#define SS 2048
#define DD 1024
#define HH 16
#define DHH 64
#define MM (BB * SS) // 4096

typedef float f32x4 __attribute__((ext_vector_type(4)));
typedef float f32x16 __attribute__((ext_vector_type(16)));
typedef __bf16 bf16x8 __attribute__((ext_vector_type(8)));
typedef unsigned int u32x2 __attribute__((ext_vector_type(2)));

#define N_QKV ((size_t)MM * DD)
#define N_W   ((size_t)DD * DD)

// ---- fallback scratch (used only if ws_size is too small) -----------------
__device__ unsigned short g_X [3][N_QKV];   // bf16 activations
__device__ unsigned short g_Q [N_QKV];      // bf16 Q*0.125*log2e  [m][n]
__device__ unsigned short g_K [N_QKV];      // bf16 K        [m][n]
__device__ unsigned short g_Vt[N_QKV];      // bf16 V^T [b][h][dh][s]
__device__ unsigned short g_Wt[3][N_W];     // bf16 Wt[n][k]

// fp32 -> bf16 RNE
__device__ __forceinline__ unsigned short f2bu(float f) {
    unsigned u = __float_as_uint(f);
    unsigned r = u + 0x7FFFu + ((u >> 16) & 1u);
    return (unsigned short)(r >> 16);
}

union FragU { uint4 u; bf16x8 v; unsigned short s[8]; };
static __device__ __forceinline__ bf16x8 ldfrag(const unsigned short* p) {
    FragU f; f.u = *(const uint4*)p; return f.v;
}

// pack two f32 -> one u32 of 2xbf16 (compiler emits v_cvt_pk_bf16_f32)
static __device__ __forceinline__ unsigned pkbf(float a, float b) {
    union { __bf16 h[2]; unsigned u; } w;
    w.h[0] = (__bf16)a; w.h[1] = (__bf16)b;
    return w.u;
}

// raw v_exp_f32 (arg already in log2 domain; ocml exp2f adds range-fixup VALU)
static __device__ __forceinline__ float fexp2(float x) {
#if __has_builtin(__builtin_amdgcn_exp2f)
    return __builtin_amdgcn_exp2f(x);
#else
    float r;
    asm("v_exp_f32 %0, %1" : "=v"(r) : "v"(x));
    return r;
#endif
}

// lane[i] <-> lane[i+32] half-exchange producing BOTH PV A-frag words:
//   new_a[l] = l<32 ? a[l]    : b[l-32]
//   new_b[l] = l<32 ? a[l+32] : b[l]
// v_permlane32_swap_b32: 1 VALU op, no LDS traffic (ds_bpermute fallback was
// the 2^22 conflict-cycle source). Inline asm when the builtin is absent.
static __device__ __forceinline__ void plswap(unsigned &a, unsigned &b) {
#if __has_builtin(__builtin_amdgcn_permlane32_swap)
    u32x2 r = __builtin_amdgcn_permlane32_swap((int)a, (int)b, false, false);
    a = r[0]; b = r[1];
#else
    asm volatile("v_permlane32_swap_b32 %0, %1" : "+v"(a), "+v"(b));
#endif
}

// ---------------------------------------------------------------------------
// Activations fp32 -> bf16, merged. Grid (4096, 3).
__global__ __launch_bounds__(256) void cvt3(
        const float* __restrict__ x0, const float* __restrict__ x1,
        const float* __restrict__ x2, unsigned short* __restrict__ X)
{
    const float* src = blockIdx.y == 0 ? x0 : (blockIdx.y == 1 ? x1 : x2);
    unsigned short* dst = X + (size_t)blockIdx.y * N_QKV;
    const size_t i = ((size_t)blockIdx.x * 256 + threadIdx.x) * 4;
    const float4 v = *(const float4*)(src + i);
    ushort4 s;
    s.x = f2bu(v.x); s.y = f2bu(v.y); s.z = f2bu(v.z); s.w = f2bu(v.w);
    *(ushort4*)(dst + i) = s;
}

// ---------------------------------------------------------------------------
// Wt[n][k] = bf16(W[k][n]), merged. Grid (16,16,3).
__global__ __launch_bounds__(256) void transpose_w3(
        const float* __restrict__ W0, const float* __restrict__ W1,
        const float* __restrict__ W2, unsigned short* __restrict__ Wt3)
{
    const float* W = blockIdx.z == 0 ? W0 : (blockIdx.z == 1 ? W1 : W2);
    unsigned short* Wt = Wt3 + (size_t)blockIdx.z * N_W;
    __shared__ float Ts[64][65];
    const int t = threadIdx.x;
    const int k0 = blockIdx.y * 64, n0 = blockIdx.x * 64;
#pragma unroll
    for (int i = 0; i < 16; ++i) {
        const int f = t + 256 * i, r = f >> 6, c = f & 63;
        Ts[r][c] = W[(size_t)(k0 + r) * DD + n0 + c];
    }
    __syncthreads();
#pragma unroll
    for (int i = 0; i < 16; ++i) {
        const int f = t + 256 * i, r = f >> 6, c = f & 63;
        Wt[(size_t)(n0 + r) * DD + k0 + c] = f2bu(Ts[c][r]);
    }
}

// ---------------------------------------------------------------------------
// Merged projection GEMM: z=0 Q (scale (1/8)*log2e so attn can use exp2),
// z=1 K, z=2 V^T. 128x128 tile, BK=64, scalar-register prefetch. Grid (8,32,3).
__global__ __launch_bounds__(256) void proj3(
        const unsigned short* __restrict__ X, const unsigned short* __restrict__ Wt3,
        const float* __restrict__ bq, const float* __restrict__ bk,
        const float* __restrict__ bv,
        unsigned short* __restrict__ Qp, unsigned short* __restrict__ Kp,
        unsigned short* __restrict__ Vtp)
{
    const int z = blockIdx.z;
    const unsigned short* xb = X   + (size_t)z * N_QKV;
    const unsigned short* Wt = Wt3 + (size_t)z * N_W;
    const float* bias = z == 0 ? bq : (z == 1 ? bk : bv);
    const float scale = z == 0 ? 0.18033688011112042f : 1.0f; // 0.125*log2(e)

    __shared__ unsigned short As[128][72];
    __shared__ unsigned short Bs[128][72];
    const int t = threadIdx.x, lane = t & 63, w = t >> 6;
    const int q = lane >> 4, li = lane & 15;
    const int wm = (w >> 1) * 64, wn = (w & 1) * 64;
    const int m0 = blockIdx.y * 128, n0 = blockIdx.x * 128;
    const int rs = t >> 3, cs = (t & 7) * 8;   // staging row/col

    f32x4 acc[4][4];
#pragma unroll
    for (int mt = 0; mt < 4; ++mt)
#pragma unroll
        for (int nt = 0; nt < 4; ++nt) acc[mt][nt] = (f32x4)0.f;

    uint4 pa0, pa1, pa2, pa3, pb0, pb1, pb2, pb3;
#define PROJ_LD(kk) \
    pa0 = *(const uint4*)(xb + (size_t)(m0 + rs      ) * DD + (kk) + cs); \
    pa1 = *(const uint4*)(xb + (size_t)(m0 + rs + 32 ) * DD + (kk) + cs); \
    pa2 = *(const uint4*)(xb + (size_t)(m0 + rs + 64 ) * DD + (kk) + cs); \
    pa3 = *(const uint4*)(xb + (size_t)(m0 + rs + 96 ) * DD + (kk) + cs); \
    pb0 = *(const uint4*)(Wt + (size_t)(n0 + rs      ) * DD + (kk) + cs); \
    pb1 = *(const uint4*)(Wt + (size_t)(n0 + rs + 32 ) * DD + (kk) + cs); \
    pb2 = *(const uint4*)(Wt + (size_t)(n0 + rs + 64 ) * DD + (kk) + cs); \
    pb3 = *(const uint4*)(Wt + (size_t)(n0 + rs + 96 ) * DD + (kk) + cs);

    PROJ_LD(0)

    for (int kk = 0; kk < DD; kk += 64) {
        *(uint4*)&As[rs     ][cs] = pa0;
        *(uint4*)&As[rs + 32][cs] = pa1;
        *(uint4*)&As[rs + 64][cs] = pa2;
        *(uint4*)&As[rs + 96][cs] = pa3;
        *(uint4*)&Bs[rs     ][cs] = pb0;
        *(uint4*)&Bs[rs + 32][cs] = pb1;
        *(uint4*)&Bs[rs + 64][cs] = pb2;
        *(uint4*)&Bs[rs + 96][cs] = pb3;
        __syncthreads();                       // tile visible
        if (kk + 64 < DD) { PROJ_LD(kk + 64) } // prefetch overlaps MFMA phase
#pragma unroll
        for (int ks = 0; ks < 64; ks += 32) {
            bf16x8 a[4], b[4];
#pragma unroll
            for (int mt = 0; mt < 4; ++mt) a[mt] = ldfrag(&As[wm + mt * 16 + li][ks + q * 8]);
#pragma unroll
            for (int nt = 0; nt < 4; ++nt) b[nt] = ldfrag(&Bs[wn + nt * 16 + li][ks + q * 8]);
#pragma unroll
            for (int mt = 0; mt < 4; ++mt)
#pragma unroll
                for (int nt = 0; nt < 4; ++nt)
                    acc[mt][nt] = __builtin_amdgcn_mfma_f32_16x16x32_bf16(
                        a[mt], b[nt], acc[mt][nt], 0, 0, 0);
        }
        __syncthreads();                       // reads done before overwrite
    }
#undef PROJ_LD

    float bvv[4];
#pragma unroll
    for (int nt = 0; nt < 4; ++nt) bvv[nt] = bias[n0 + wn + nt * 16 + li];

    if (z < 2) {
        unsigned short* out = z == 0 ? Qp : Kp;
#pragma unroll
        for (int mt = 0; mt < 4; ++mt)
#pragma unroll
            for (int nt = 0; nt < 4; ++nt)
#pragma unroll
                for (int reg = 0; reg < 4; ++reg) {
                    const int m = m0 + wm + mt * 16 + q * 4 + reg;
                    out[(size_t)m * DD + n0 + wn + nt * 16 + li] =
                        f2bu((acc[mt][nt][reg] + bvv[nt]) * scale);
                }
    } else {
        const int b = m0 >> 11;          // 128-row m-tiles never cross batch
        const int h = (n0 + wn) >> 6;    // 64-wide wave n-slice == one head
#pragma unroll
        for (int mt = 0; mt < 4; ++mt)
#pragma unroll
            for (int nt = 0; nt < 4; ++nt) {
                const int s = (m0 & (SS - 1)) + wm + mt * 16 + q * 4;
                const int dh = nt * 16 + li;
                ushort4 sv;
                sv.x = f2bu(acc[mt][nt][0] + bvv[nt]);
                sv.y = f2bu(acc[mt][nt][1] + bvv[nt]);
                sv.z = f2bu(acc[mt][nt][2] + bvv[nt]);
                sv.w = f2bu(acc[mt][nt][3] + bvv[nt]);
                *(ushort4*)(Vtp + ((size_t)((b * HH + h) * DHH + dh)) * SS + s) = sv;
            }
    }
}

// ---------------------------------------------------------------------------
// attn7: KV-split-in-block flash attention (8 waves, 512 threads).
//   Diagnosis of attn6 (60.9us): MfmaUtil 23 / VALUBusy 49 / HBM 20 / Occ 17.6
//   -> latency-stall-bound at 2 waves/SIMD (total waves fixed: 65536 q-rows /
//   32 per wave = 2048 = 2/SIMD). The no-max softmax has NO running max, so
//   partial (o,l) over disjoint KV ranges combine by PURE ADDITION:
//     waves 0-3: kt 0..15, waves 4-7: kt 16..31, same 128 q-rows.
//   -> 4096 waves = 4/SIMD. Two independent K/V dbuf streams in LDS (64KB);
//   final combine via LDS (o aliased onto dead K/V; [j][256] conflict-free).
//   permlane32_swap via inline asm when builtin absent (kills ds_bpermute).
// Grid (16,16,2), 512 threads.
__global__ __launch_bounds__(512, 4) void attn7(
        const unsigned short* __restrict__ Qg, const unsigned short* __restrict__ Kg,
        const unsigned short* __restrict__ Vtg,
        const float* __restrict__ queries, float* __restrict__ outp)
{
    __shared__ unsigned short KVb[2][2][2][64][64]; // [group][K/V][dbuf][row][slot8*8] 64KB
    __shared__ float Lp[2][4][32];                  // [group][wave][q-row]

    const int t = threadIdx.x, lane = t & 63;
    const int g  = t >> 8;              // kv-half group (0: kt 0-15, 1: kt 16-31)
    const int wg = (t >> 6) & 3;        // wave-within-group = q-subtile
    const int col = lane & 31;          // q-row (QK) / dh (PV) owned by lane
    const int hi  = lane >> 5;
    const int qt = blockIdx.x, h = blockIdx.y, b = blockIdx.z;

    const int tg = t & 255;
    const int sr = tg >> 3;             // staging row 0..31
    const int sc = tg & 7;              // staging 16B slot

    unsigned short (*Kb)[64][64] = KVb[g][0];
    unsigned short (*Vb)[64][64] = KVb[g][1];

    const unsigned short* Kbase = Kg  + (size_t)(b * SS) * DD + h * DHH;
    const unsigned short* Vbase = Vtg + ((size_t)((b * HH + h) * DHH)) * SS;

    // Q fragments: lane holds Q[q = qt*128 + wg*32 + col][d = i*16 + hi*8 + j]
    bf16x8 qa[4];
    {
        const unsigned short* qp =
            Qg + (size_t)(b * SS + qt * 128 + wg * 32 + col) * DD + h * DHH + hi * 8;
#pragma unroll
        for (int i = 0; i < 4; ++i) qa[i] = ldfrag(qp + i * 16);
    }

    f32x16 o0 = (f32x16)0.f, o1 = (f32x16)0.f;
    float lsum = 0.f;
    const int xr = col & 7;             // read-side swizzle key (same for col+32)
    const int kvofs = g << 10;          // this group's kv base (g*16 tiles * 64)

    uint4 k0, k1, v0, v1;
#define LD_TILE(s0) \
    k0 = *(const uint4*)(Kbase + (size_t)((s0) + sr     ) * DD + sc * 8); \
    k1 = *(const uint4*)(Kbase + (size_t)((s0) + sr + 32) * DD + sc * 8); \
    v0 = *(const uint4*)(Vbase + (size_t)(sr     ) * SS + (s0) + sc * 8); \
    v1 = *(const uint4*)(Vbase + (size_t)(sr + 32) * SS + (s0) + sc * 8);

#define ST_TILE(buf) \
    *(uint4*)&Kb[buf][sr     ][(sc ^ (sr & 7)) * 8] = k0; \
    *(uint4*)&Kb[buf][sr + 32][(sc ^ (sr & 7)) * 8] = k1; \
    *(uint4*)&Vb[buf][sr     ][(sc ^ (sr & 7)) * 8] = v0; \
    *(uint4*)&Vb[buf][sr + 32][(sc ^ (sr & 7)) * 8] = v1;

    LD_TILE(kvofs)
    ST_TILE(0)
    __syncthreads();

    const int NT = 16;                  // tiles per group
#pragma unroll 2
    for (int kt = 0; kt < NT; ++kt) {
        const int cur = kt & 1;
        if (kt + 1 < NT) { LD_TILE(kvofs + (kt + 1) * 64) }  // issue early (T14)

        // S^T = K Q^T : two independent 4-chains (k rows 0-31, 32-63)
        f32x16 st0 = (f32x16)0.f, st1 = (f32x16)0.f;
#pragma unroll
        for (int i = 0; i < 4; ++i) {
            const int slot = ((i * 2 + hi) ^ xr) * 8;
            bf16x8 ka0 = ldfrag(&Kb[cur][col     ][slot]);
            bf16x8 ka1 = ldfrag(&Kb[cur][col + 32][slot]);
            st0 = __builtin_amdgcn_mfma_f32_32x32x16_bf16(ka0, qa[i], st0, 0, 0, 0);
            st1 = __builtin_amdgcn_mfma_f32_32x32x16_bf16(ka1, qa[i], st1, 0, 0, 0);
        }

        // P = exp2(S^T) in regs; pack to bf16 pairs; tree-summed l
        unsigned pkw[4][4];
        {
            float pe0[16], pe1[16];
#pragma unroll
            for (int r = 0; r < 16; ++r) { pe0[r] = fexp2(st0[r]); }
#pragma unroll
            for (int r = 0; r < 16; ++r) { pe1[r] = fexp2(st1[r]); }
            float s4[4] = {0.f, 0.f, 0.f, 0.f};
#pragma unroll
            for (int r = 0; r < 16; r += 4) {
                s4[0] += pe0[r] + pe1[r];
                s4[1] += pe0[r + 1] + pe1[r + 1];
                s4[2] += pe0[r + 2] + pe1[r + 2];
                s4[3] += pe0[r + 3] + pe1[r + 3];
            }
            lsum += (s4[0] + s4[1]) + (s4[2] + s4[3]);
#pragma unroll
            for (int s = 0; s < 2; ++s) {
                pkw[s][0]     = pkbf(pe0[8 * s + 0], pe0[8 * s + 1]);
                pkw[s][1]     = pkbf(pe0[8 * s + 2], pe0[8 * s + 3]);
                pkw[s][2]     = pkbf(pe0[8 * s + 4], pe0[8 * s + 5]);
                pkw[s][3]     = pkbf(pe0[8 * s + 6], pe0[8 * s + 7]);
                pkw[2 + s][0] = pkbf(pe1[8 * s + 0], pe1[8 * s + 1]);
                pkw[2 + s][1] = pkbf(pe1[8 * s + 2], pe1[8 * s + 3]);
                pkw[2 + s][2] = pkbf(pe1[8 * s + 4], pe1[8 * s + 5]);
                pkw[2 + s][3] = pkbf(pe1[8 * s + 6], pe1[8 * s + 7]);
            }
        }

        // write-late staging (T14): prev readers passed the last barrier
        if (kt + 1 < NT) { ST_TILE(cur ^ 1) }

        // PV: per 16-k chunk, permlane32_swap yields words 0/2 (and 1/3)
#pragma unroll
        for (int c = 0; c < 4; ++c) {
            unsigned a0 = pkw[c][0], b0 = pkw[c][2];
            unsigned a1 = pkw[c][1], b1 = pkw[c][3];
            plswap(a0, b0);
            plswap(a1, b1);
            FragU pf;
            pf.u.x = a0; pf.u.y = a1; pf.u.z = b0; pf.u.w = b1;

            const int vs = ((c * 2 + hi) ^ xr) * 8;
            bf16x8 vb0 = ldfrag(&Vb[cur][col     ][vs]);
            bf16x8 vb1 = ldfrag(&Vb[cur][col + 32][vs]);
            o0 = __builtin_amdgcn_mfma_f32_32x32x16_bf16(pf.v, vb0, o0, 0, 0, 0);
            o1 = __builtin_amdgcn_mfma_f32_32x32x16_bf16(pf.v, vb1, o1, 0, 0, 0);
        }
        __syncthreads();               // tile cur fully consumed; cur^1 ready
    }
#undef LD_TILE
#undef ST_TILE

    // combine the two kv-halves: pure (o,l) addition (no-max softmax)
    const float lt = lsum + __shfl_xor(lsum, 32);   // this half's full l for q-row col
    float* Ob = (float*)KVb;                        // 32KB alias on dead K/V
    const int obase = wg * 64 + lane;
    if (g == 1) {
#pragma unroll
        for (int r = 0; r < 16; ++r) {
            Ob[r * 256 + obase]        = o0[r];
            Ob[(16 + r) * 256 + obase] = o1[r];
        }
    }
    if (lane < 32) Lp[g][wg][lane] = lt;
    __syncthreads();

    if (g == 0) {
        // epilogue: rows = crow(reg,hi), cols = lane&31 (+32 for o1)
        const size_t gbase = (size_t)(b * SS + qt * 128 + wg * 32) * DD + h * DHH + col;
#pragma unroll
        for (int reg = 0; reg < 16; ++reg) {
            const int rl = (reg & 3) + 8 * (reg >> 2) + 4 * hi;
            const float li = 1.f / (Lp[0][wg][rl] + Lp[1][wg][rl]);
            const size_t gaddr = gbase + (size_t)rl * DD;
            outp[gaddr]      = (o0[reg] + Ob[reg * 256 + obase]) * li + queries[gaddr];
            outp[gaddr + 32] = (o1[reg] + Ob[(16 + reg) * 256 + obase]) * li + queries[gaddr + 32];
        }
    }
}

// ---------------------------------------------------------------------------
extern "C" void kernel_launch(void* const* d_in, const int* in_sizes, int n_in,
                              void* d_out, int out_size, void* d_ws, size_t ws_size,
                              hipStream_t stream) {
    const float* queries = (const float*)d_in[0];
    const float* keys    = (const float*)d_in[1];
    const float* values  = (const float*)d_in[2];
    const float* Wq      = (const float*)d_in[3];
    const float* bq      = (const float*)d_in[4];
    const float* Wk      = (const float*)d_in[5];
    const float* bk      = (const float*)d_in[6];
    const float* Wv      = (const float*)d_in[7];
    const float* bv      = (const float*)d_in[8];
    float* outp = (float*)d_out;

    // scratch: prefer d_ws (54 MB needed); fall back to device globals.
    const size_t need = (6 * N_QKV + 3 * N_W) * sizeof(unsigned short);
    unsigned short *Xp, *Qp, *Kp, *Vtp, *Wtp;
    if (ws_size >= need) {
        Xp  = (unsigned short*)d_ws;
        Qp  = Xp + 3 * N_QKV;
        Kp  = Qp + N_QKV;
        Vtp = Kp + N_QKV;
        Wtp = Vtp + N_QKV;
    } else {
        hipGetSymbolAddress((void**)&Xp,  HIP_SYMBOL(g_X));
        hipGetSymbolAddress((void**)&Qp,  HIP_SYMBOL(g_Q));
        hipGetSymbolAddress((void**)&Kp,  HIP_SYMBOL(g_K));
        hipGetSymbolAddress((void**)&Vtp, HIP_SYMBOL(g_Vt));
        hipGetSymbolAddress((void**)&Wtp, HIP_SYMBOL(g_Wt));
    }

    const dim3 bp(256);
    cvt3<<<dim3(MM * DD / 1024, 3), bp, 0, stream>>>(queries, keys, values, Xp);
    transpose_w3<<<dim3(16, 16, 3), bp, 0, stream>>>(Wq, Wk, Wv, Wtp);
    proj3<<<dim3(8, 32, 3), bp, 0, stream>>>(Xp, Wtp, bq, bk, bv, Qp, Kp, Vtp);
    attn7<<<dim3(SS / 128, HH, BB), dim3(512), 0, stream>>>(Qp, Kp, Vtp, queries, outp);
}

// Round 5
// 202.725 us; speedup vs baseline: 1.2171x; 1.2171x over previous
//
#include <hip/hip_runtime.h>
#include <hip/hip_bf16.h>
#include <math.h>

// Problem constants
#define BB 2
#define SS 2048
#define DD 1024
#define HH 16
#define DHH 64
#define MM (BB * SS) // 4096

typedef float f32x4 __attribute__((ext_vector_type(4)));
typedef float f32x16 __attribute__((ext_vector_type(16)));
typedef __bf16 bf16x8 __attribute__((ext_vector_type(8)));
typedef unsigned int u32x2 __attribute__((ext_vector_type(2)));

#define N_QKV ((size_t)MM * DD)
#define N_W   ((size_t)DD * DD)

// ---- fallback scratch (used only if ws_size is too small) -----------------
__device__ unsigned short g_X [3][N_QKV];   // bf16 activations
__device__ unsigned short g_Q [N_QKV];      // bf16 Q*0.125*log2e  [m][n]
__device__ unsigned short g_K [N_QKV];      // bf16 K        [m][n]
__device__ unsigned short g_Vt[N_QKV];      // bf16 V^T [b][h][dh][s]
__device__ unsigned short g_Wt[3][N_W];     // bf16 Wt[n][k]

// fp32 -> bf16 RNE
__device__ __forceinline__ unsigned short f2bu(float f) {
    unsigned u = __float_as_uint(f);
    unsigned r = u + 0x7FFFu + ((u >> 16) & 1u);
    return (unsigned short)(r >> 16);
}

union FragU { uint4 u; bf16x8 v; unsigned short s[8]; };
static __device__ __forceinline__ bf16x8 ldfrag(const unsigned short* p) {
    FragU f; f.u = *(const uint4*)p; return f.v;
}

// pack two f32 -> one u32 of 2xbf16 (compiler emits v_cvt_pk_bf16_f32)
static __device__ __forceinline__ unsigned pkbf(float a, float b) {
    union { __bf16 h[2]; unsigned u; } w;
    w.h[0] = (__bf16)a; w.h[1] = (__bf16)b;
    return w.u;
}

// raw v_exp_f32 (arg already in log2 domain; ocml exp2f adds range-fixup VALU)
static __device__ __forceinline__ float fexp2(float x) {
#if __has_builtin(__builtin_amdgcn_exp2f)
    return __builtin_amdgcn_exp2f(x);
#else
    float r;
    asm("v_exp_f32 %0, %1" : "=v"(r) : "v"(x));
    return r;
#endif
}

// lane[i] <-> lane[i+32] half-exchange producing BOTH PV A-frag words:
//   new_a[l] = l<32 ? a[l]    : b[l-32]
//   new_b[l] = l<32 ? a[l+32] : b[l]
static __device__ __forceinline__ void plswap(unsigned &a, unsigned &b) {
#if __has_builtin(__builtin_amdgcn_permlane32_swap)
    u32x2 r = __builtin_amdgcn_permlane32_swap((int)a, (int)b, false, false);
    a = r[0]; b = r[1];
#else
    asm volatile("v_permlane32_swap_b32 %0, %1" : "+v"(a), "+v"(b));
#endif
}

// ---------------------------------------------------------------------------
// Activations fp32 -> bf16, merged. Grid (4096, 3).
__global__ __launch_bounds__(256) void cvt3(
        const float* __restrict__ x0, const float* __restrict__ x1,
        const float* __restrict__ x2, unsigned short* __restrict__ X)
{
    const float* src = blockIdx.y == 0 ? x0 : (blockIdx.y == 1 ? x1 : x2);
    unsigned short* dst = X + (size_t)blockIdx.y * N_QKV;
    const size_t i = ((size_t)blockIdx.x * 256 + threadIdx.x) * 4;
    const float4 v = *(const float4*)(src + i);
    ushort4 s;
    s.x = f2bu(v.x); s.y = f2bu(v.y); s.z = f2bu(v.z); s.w = f2bu(v.w);
    *(ushort4*)(dst + i) = s;
}

// ---------------------------------------------------------------------------
// Wt[n][k] = bf16(W[k][n]), merged. Grid (16,16,3).
__global__ __launch_bounds__(256) void transpose_w3(
        const float* __restrict__ W0, const float* __restrict__ W1,
        const float* __restrict__ W2, unsigned short* __restrict__ Wt3)
{
    const float* W = blockIdx.z == 0 ? W0 : (blockIdx.z == 1 ? W1 : W2);
    unsigned short* Wt = Wt3 + (size_t)blockIdx.z * N_W;
    __shared__ float Ts[64][65];
    const int t = threadIdx.x;
    const int k0 = blockIdx.y * 64, n0 = blockIdx.x * 64;
#pragma unroll
    for (int i = 0; i < 16; ++i) {
        const int f = t + 256 * i, r = f >> 6, c = f & 63;
        Ts[r][c] = W[(size_t)(k0 + r) * DD + n0 + c];
    }
    __syncthreads();
#pragma unroll
    for (int i = 0; i < 16; ++i) {
        const int f = t + 256 * i, r = f >> 6, c = f & 63;
        Wt[(size_t)(n0 + r) * DD + k0 + c] = f2bu(Ts[c][r]);
    }
}

// ---------------------------------------------------------------------------
// Merged projection GEMM: z=0 Q (scale (1/8)*log2e so attn can use exp2),
// z=1 K, z=2 V^T. 128x128 tile, BK=64, scalar-register prefetch. Grid (8,32,3).
__global__ __launch_bounds__(256) void proj3(
        const unsigned short* __restrict__ X, const unsigned short* __restrict__ Wt3,
        const float* __restrict__ bq, const float* __restrict__ bk,
        const float* __restrict__ bv,
        unsigned short* __restrict__ Qp, unsigned short* __restrict__ Kp,
        unsigned short* __restrict__ Vtp)
{
    const int z = blockIdx.z;
    const unsigned short* xb = X   + (size_t)z * N_QKV;
    const unsigned short* Wt = Wt3 + (size_t)z * N_W;
    const float* bias = z == 0 ? bq : (z == 1 ? bk : bv);
    const float scale = z == 0 ? 0.18033688011112042f : 1.0f; // 0.125*log2(e)

    __shared__ unsigned short As[128][72];
    __shared__ unsigned short Bs[128][72];
    const int t = threadIdx.x, lane = t & 63, w = t >> 6;
    const int q = lane >> 4, li = lane & 15;
    const int wm = (w >> 1) * 64, wn = (w & 1) * 64;
    const int m0 = blockIdx.y * 128, n0 = blockIdx.x * 128;
    const int rs = t >> 3, cs = (t & 7) * 8;   // staging row/col

    f32x4 acc[4][4];
#pragma unroll
    for (int mt = 0; mt < 4; ++mt)
#pragma unroll
        for (int nt = 0; nt < 4; ++nt) acc[mt][nt] = (f32x4)0.f;

    uint4 pa0, pa1, pa2, pa3, pb0, pb1, pb2, pb3;
#define PROJ_LD(kk) \
    pa0 = *(const uint4*)(xb + (size_t)(m0 + rs      ) * DD + (kk) + cs); \
    pa1 = *(const uint4*)(xb + (size_t)(m0 + rs + 32 ) * DD + (kk) + cs); \
    pa2 = *(const uint4*)(xb + (size_t)(m0 + rs + 64 ) * DD + (kk) + cs); \
    pa3 = *(const uint4*)(xb + (size_t)(m0 + rs + 96 ) * DD + (kk) + cs); \
    pb0 = *(const uint4*)(Wt + (size_t)(n0 + rs      ) * DD + (kk) + cs); \
    pb1 = *(const uint4*)(Wt + (size_t)(n0 + rs + 32 ) * DD + (kk) + cs); \
    pb2 = *(const uint4*)(Wt + (size_t)(n0 + rs + 64 ) * DD + (kk) + cs); \
    pb3 = *(const uint4*)(Wt + (size_t)(n0 + rs + 96 ) * DD + (kk) + cs);

    PROJ_LD(0)

    for (int kk = 0; kk < DD; kk += 64) {
        *(uint4*)&As[rs     ][cs] = pa0;
        *(uint4*)&As[rs + 32][cs] = pa1;
        *(uint4*)&As[rs + 64][cs] = pa2;
        *(uint4*)&As[rs + 96][cs] = pa3;
        *(uint4*)&Bs[rs     ][cs] = pb0;
        *(uint4*)&Bs[rs + 32][cs] = pb1;
        *(uint4*)&Bs[rs + 64][cs] = pb2;
        *(uint4*)&Bs[rs + 96][cs] = pb3;
        __syncthreads();                       // tile visible
        if (kk + 64 < DD) { PROJ_LD(kk + 64) } // prefetch overlaps MFMA phase
#pragma unroll
        for (int ks = 0; ks < 64; ks += 32) {
            bf16x8 a[4], b[4];
#pragma unroll
            for (int mt = 0; mt < 4; ++mt) a[mt] = ldfrag(&As[wm + mt * 16 + li][ks + q * 8]);
#pragma unroll
            for (int nt = 0; nt < 4; ++nt) b[nt] = ldfrag(&Bs[wn + nt * 16 + li][ks + q * 8]);
#pragma unroll
            for (int mt = 0; mt < 4; ++mt)
#pragma unroll
                for (int nt = 0; nt < 4; ++nt)
                    acc[mt][nt] = __builtin_amdgcn_mfma_f32_16x16x32_bf16(
                        a[mt], b[nt], acc[mt][nt], 0, 0, 0);
        }
        __syncthreads();                       // reads done before overwrite
    }
#undef PROJ_LD

    float bvv[4];
#pragma unroll
    for (int nt = 0; nt < 4; ++nt) bvv[nt] = bias[n0 + wn + nt * 16 + li];

    if (z < 2) {
        unsigned short* out = z == 0 ? Qp : Kp;
#pragma unroll
        for (int mt = 0; mt < 4; ++mt)
#pragma unroll
            for (int nt = 0; nt < 4; ++nt)
#pragma unroll
                for (int reg = 0; reg < 4; ++reg) {
                    const int m = m0 + wm + mt * 16 + q * 4 + reg;
                    out[(size_t)m * DD + n0 + wn + nt * 16 + li] =
                        f2bu((acc[mt][nt][reg] + bvv[nt]) * scale);
                }
    } else {
        const int b = m0 >> 11;          // 128-row m-tiles never cross batch
        const int h = (n0 + wn) >> 6;    // 64-wide wave n-slice == one head
#pragma unroll
        for (int mt = 0; mt < 4; ++mt)
#pragma unroll
            for (int nt = 0; nt < 4; ++nt) {
                const int s = (m0 & (SS - 1)) + wm + mt * 16 + q * 4;
                const int dh = nt * 16 + li;
                ushort4 sv;
                sv.x = f2bu(acc[mt][nt][0] + bvv[nt]);
                sv.y = f2bu(acc[mt][nt][1] + bvv[nt]);
                sv.z = f2bu(acc[mt][nt][2] + bvv[nt]);
                sv.w = f2bu(acc[mt][nt][3] + bvv[nt]);
                *(ushort4*)(Vtp + ((size_t)((b * HH + h) * DHH + dh)) * SS + s) = sv;
            }
    }
}

// ---------------------------------------------------------------------------
// attn8: KV-split-in-block flash attention (8 waves, 512 threads).
//   vs attn7 (103.8us): __launch_bounds__(512,4) forced VGPR=64 -> ~120MB
//   spill round-trip (FETCH 196MB / WRITE 136MB). Fix: (512,2) -> VGPR cap
//   >=128, no spill; occupancy LDS-limited at 2 blocks/CU = 4 waves/SIMD.
//   Also: two-level XOR swizzle (slot ^= (row ^ row>>3) & 7). Row pitch is
//   128B so bank bits come only from the slot; lanes {col,col+8,col+16,
//   col+24} share col&7 -> 4-way read conflict under the 1-level swizzle.
//   XORing the high row bits spreads the quad to 4 distinct slots.
//   exp/pack in 8-wide chunks (shorter pe liveness); pairwise-tree lsum.
// Grid (16,16,2), 512 threads.
__global__ __launch_bounds__(512, 2) void attn8(
        const unsigned short* __restrict__ Qg, const unsigned short* __restrict__ Kg,
        const unsigned short* __restrict__ Vtg,
        const float* __restrict__ queries, float* __restrict__ outp)
{
    __shared__ unsigned short KVb[2][2][2][64][64]; // [group][K/V][dbuf][row][slot8*8] 64KB
    __shared__ float Lp[2][4][32];                  // [group][wave][q-row]

    const int t = threadIdx.x, lane = t & 63;
    const int g  = t >> 8;              // kv-half group (0: kt 0-15, 1: kt 16-31)
    const int wg = (t >> 6) & 3;        // wave-within-group = q-subtile
    const int col = lane & 31;          // q-row (QK) / dh (PV) owned by lane
    const int hi  = lane >> 5;
    const int qt = blockIdx.x, h = blockIdx.y, b = blockIdx.z;

    const int tg = t & 255;
    const int sr = tg >> 3;             // staging row 0..31
    const int sc = tg & 7;              // staging 16B slot

    unsigned short (*Kb)[64][64] = KVb[g][0];
    unsigned short (*Vb)[64][64] = KVb[g][1];

    const unsigned short* Kbase = Kg  + (size_t)(b * SS) * DD + h * DHH;
    const unsigned short* Vbase = Vtg + ((size_t)((b * HH + h) * DHH)) * SS;

    // Q fragments: lane holds Q[q = qt*128 + wg*32 + col][d = i*16 + hi*8 + j]
    bf16x8 qa[4];
    {
        const unsigned short* qp =
            Qg + (size_t)(b * SS + qt * 128 + wg * 32 + col) * DD + h * DHH + hi * 8;
#pragma unroll
        for (int i = 0; i < 4; ++i) qa[i] = ldfrag(qp + i * 16);
    }

    f32x16 o0 = (f32x16)0.f, o1 = (f32x16)0.f;
    float lsum = 0.f;
    // two-level swizzle keys: f(row) = (row ^ (row>>3)) & 7; f(row+32)=f(row)^4
    const int xr2 = (col ^ (col >> 3)) & 7;    // read key for rows col / col+32
    const int wsw = (sr ^ (sr >> 3)) & 7;      // write key for rows sr / sr+32
    const int kvofs = g << 10;                 // group kv base (g*16 tiles * 64)

    uint4 k0, k1, v0, v1;
#define LD_TILE(s0) \
    k0 = *(const uint4*)(Kbase + (size_t)((s0) + sr     ) * DD + sc * 8); \
    k1 = *(const uint4*)(Kbase + (size_t)((s0) + sr + 32) * DD + sc * 8); \
    v0 = *(const uint4*)(Vbase + (size_t)(sr     ) * SS + (s0) + sc * 8); \
    v1 = *(const uint4*)(Vbase + (size_t)(sr + 32) * SS + (s0) + sc * 8);

#define ST_TILE(buf) \
    *(uint4*)&Kb[buf][sr     ][(sc ^ wsw) * 8]     = k0; \
    *(uint4*)&Kb[buf][sr + 32][(sc ^ wsw ^ 4) * 8] = k1; \
    *(uint4*)&Vb[buf][sr     ][(sc ^ wsw) * 8]     = v0; \
    *(uint4*)&Vb[buf][sr + 32][(sc ^ wsw ^ 4) * 8] = v1;

    LD_TILE(kvofs)
    ST_TILE(0)
    __syncthreads();

    const int NT = 16;                  // tiles per group
#pragma unroll 2
    for (int kt = 0; kt < NT; ++kt) {
        const int cur = kt & 1;
        if (kt + 1 < NT) { LD_TILE(kvofs + (kt + 1) * 64) }  // issue early (T14)

        // S^T = K Q^T : two independent 4-chains (k rows 0-31, 32-63)
        f32x16 st0 = (f32x16)0.f, st1 = (f32x16)0.f;
#pragma unroll
        for (int i = 0; i < 4; ++i) {
            const int sl = (i * 2 + hi) ^ xr2;
            bf16x8 ka0 = ldfrag(&Kb[cur][col     ][sl * 8]);
            bf16x8 ka1 = ldfrag(&Kb[cur][col + 32][(sl ^ 4) * 8]);
            st0 = __builtin_amdgcn_mfma_f32_32x32x16_bf16(ka0, qa[i], st0, 0, 0, 0);
            st1 = __builtin_amdgcn_mfma_f32_32x32x16_bf16(ka1, qa[i], st1, 0, 0, 0);
        }

        // P = exp2(S^T) in regs, 8-wide chunks (short pe liveness); tree lsum
        unsigned pkw[4][4];
        float ls = 0.f;
#pragma unroll
        for (int s = 0; s < 2; ++s) {
            float pe[8];
#pragma unroll
            for (int r = 0; r < 8; ++r) pe[r] = fexp2(st0[8 * s + r]);
            ls += ((pe[0] + pe[1]) + (pe[2] + pe[3])) + ((pe[4] + pe[5]) + (pe[6] + pe[7]));
            pkw[s][0] = pkbf(pe[0], pe[1]); pkw[s][1] = pkbf(pe[2], pe[3]);
            pkw[s][2] = pkbf(pe[4], pe[5]); pkw[s][3] = pkbf(pe[6], pe[7]);
        }
#pragma unroll
        for (int s = 0; s < 2; ++s) {
            float pe[8];
#pragma unroll
            for (int r = 0; r < 8; ++r) pe[r] = fexp2(st1[8 * s + r]);
            ls += ((pe[0] + pe[1]) + (pe[2] + pe[3])) + ((pe[4] + pe[5]) + (pe[6] + pe[7]));
            pkw[2 + s][0] = pkbf(pe[0], pe[1]); pkw[2 + s][1] = pkbf(pe[2], pe[3]);
            pkw[2 + s][2] = pkbf(pe[4], pe[5]); pkw[2 + s][3] = pkbf(pe[6], pe[7]);
        }
        lsum += ls;

        // write-late staging (T14): prev readers passed the last barrier
        if (kt + 1 < NT) { ST_TILE(cur ^ 1) }

        // PV: per 16-k chunk, permlane32_swap yields words 0/2 (and 1/3)
#pragma unroll
        for (int c = 0; c < 4; ++c) {
            unsigned a0 = pkw[c][0], b0 = pkw[c][2];
            unsigned a1 = pkw[c][1], b1 = pkw[c][3];
            plswap(a0, b0);
            plswap(a1, b1);
            FragU pf;
            pf.u.x = a0; pf.u.y = a1; pf.u.z = b0; pf.u.w = b1;

            const int vl = (c * 2 + hi) ^ xr2;
            bf16x8 vb0 = ldfrag(&Vb[cur][col     ][vl * 8]);
            bf16x8 vb1 = ldfrag(&Vb[cur][col + 32][(vl ^ 4) * 8]);
            o0 = __builtin_amdgcn_mfma_f32_32x32x16_bf16(pf.v, vb0, o0, 0, 0, 0);
            o1 = __builtin_amdgcn_mfma_f32_32x32x16_bf16(pf.v, vb1, o1, 0, 0, 0);
        }
        __syncthreads();               // tile cur fully consumed; cur^1 ready
    }
#undef LD_TILE
#undef ST_TILE

    // combine the two kv-halves: pure (o,l) addition (no-max softmax)
    const float lt = lsum + __shfl_xor(lsum, 32);   // this half's full l for q-row col
    float* Ob = (float*)KVb;                        // 32KB alias on dead K/V
    const int obase = wg * 64 + lane;
    if (g == 1) {
#pragma unroll
        for (int r = 0; r < 16; ++r) {
            Ob[r * 256 + obase]        = o0[r];
            Ob[(16 + r) * 256 + obase] = o1[r];
        }
    }
    if (lane < 32) Lp[g][wg][lane] = lt;
    __syncthreads();

    if (g == 0) {
        // epilogue: rows = crow(reg,hi), cols = lane&31 (+32 for o1)
        const size_t gbase = (size_t)(b * SS + qt * 128 + wg * 32) * DD + h * DHH + col;
#pragma unroll
        for (int reg = 0; reg < 16; ++reg) {
            const int rl = (reg & 3) + 8 * (reg >> 2) + 4 * hi;
            const float li = 1.f / (Lp[0][wg][rl] + Lp[1][wg][rl]);
            const size_t gaddr = gbase + (size_t)rl * DD;
            outp[gaddr]      = (o0[reg] + Ob[reg * 256 + obase]) * li + queries[gaddr];
            outp[gaddr + 32] = (o1[reg] + Ob[(16 + reg) * 256 + obase]) * li + queries[gaddr + 32];
        }
    }
}

// ---------------------------------------------------------------------------
extern "C" void kernel_launch(void* const* d_in, const int* in_sizes, int n_in,
                              void* d_out, int out_size, void* d_ws, size_t ws_size,
                              hipStream_t stream) {
    const float* queries = (const float*)d_in[0];
    const float* keys    = (const float*)d_in[1];
    const float* values  = (const float*)d_in[2];
    const float* Wq      = (const float*)d_in[3];
    const float* bq      = (const float*)d_in[4];
    const float* Wk      = (const float*)d_in[5];
    const float* bk      = (const float*)d_in[6];
    const float* Wv      = (const float*)d_in[7];
    const float* bv      = (const float*)d_in[8];
    float* outp = (float*)d_out;

    // scratch: prefer d_ws (54 MB needed); fall back to device globals.
    const size_t need = (6 * N_QKV + 3 * N_W) * sizeof(unsigned short);
    unsigned short *Xp, *Qp, *Kp, *Vtp, *Wtp;
    if (ws_size >= need) {
        Xp  = (unsigned short*)d_ws;
        Qp  = Xp + 3 * N_QKV;
        Kp  = Qp + N_QKV;
        Vtp = Kp + N_QKV;
        Wtp = Vtp + N_QKV;
    } else {
        hipGetSymbolAddress((void**)&Xp,  HIP_SYMBOL(g_X));
        hipGetSymbolAddress((void**)&Qp,  HIP_SYMBOL(g_Q));
        hipGetSymbolAddress((void**)&Kp,  HIP_SYMBOL(g_K));
        hipGetSymbolAddress((void**)&Vtp, HIP_SYMBOL(g_Vt));
        hipGetSymbolAddress((void**)&Wtp, HIP_SYMBOL(g_Wt));
    }

    const dim3 bp(256);
    cvt3<<<dim3(MM * DD / 1024, 3), bp, 0, stream>>>(queries, keys, values, Xp);
    transpose_w3<<<dim3(16, 16, 3), bp, 0, stream>>>(Wq, Wk, Wv, Wtp);
    proj3<<<dim3(8, 32, 3), bp, 0, stream>>>(Xp, Wtp, bq, bk, bv, Qp, Kp, Vtp);
    attn8<<<dim3(SS / 128, HH, BB), dim3(512), 0, stream>>>(Qp, Kp, Vtp, queries, outp);
}

// Round 6
// 202.095 us; speedup vs baseline: 1.2209x; 1.0031x over previous
//
#include <hip/hip_runtime.h>
#include <hip/hip_bf16.h>
#include <math.h>

// Problem constants
#define BB 2
#define SS 2048
#define DD 1024
#define HH 16
#define DHH 64
#define MM (BB * SS) // 4096

typedef float f32x4 __attribute__((ext_vector_type(4)));
typedef float f32x16 __attribute__((ext_vector_type(16)));
typedef __bf16 bf16x8 __attribute__((ext_vector_type(8)));
typedef unsigned int u32x2 __attribute__((ext_vector_type(2)));

#define N_QKV ((size_t)MM * DD)
#define N_W   ((size_t)DD * DD)

// ---- fallback scratch (used only if ws_size is too small) -----------------
__device__ unsigned short g_X [3][N_QKV];   // bf16 activations
__device__ unsigned short g_Q [N_QKV];      // bf16 Q*0.125*log2e  [m][n]
__device__ unsigned short g_K [N_QKV];      // bf16 K        [m][n]
__device__ unsigned short g_Vt[N_QKV];      // bf16 V^T [b][h][dh][s]
__device__ unsigned short g_Wt[3][N_W];     // bf16 Wt[n][k]

// fp32 -> bf16 RNE
__device__ __forceinline__ unsigned short f2bu(float f) {
    unsigned u = __float_as_uint(f);
    unsigned r = u + 0x7FFFu + ((u >> 16) & 1u);
    return (unsigned short)(r >> 16);
}

union FragU { uint4 u; bf16x8 v; unsigned short s[8]; };
static __device__ __forceinline__ bf16x8 ldfrag(const unsigned short* p) {
    FragU f; f.u = *(const uint4*)p; return f.v;
}

// pack two f32 -> one u32 of 2xbf16 (compiler emits v_cvt_pk_bf16_f32)
static __device__ __forceinline__ unsigned pkbf(float a, float b) {
    union { __bf16 h[2]; unsigned u; } w;
    w.h[0] = (__bf16)a; w.h[1] = (__bf16)b;
    return w.u;
}

// raw v_exp_f32 (arg already in log2 domain; ocml exp2f adds range-fixup VALU)
static __device__ __forceinline__ float fexp2(float x) {
#if __has_builtin(__builtin_amdgcn_exp2f)
    return __builtin_amdgcn_exp2f(x);
#else
    float r;
    asm("v_exp_f32 %0, %1" : "=v"(r) : "v"(x));
    return r;
#endif
}

// lane[i] <-> lane[i+32] half-exchange producing BOTH PV A-frag words:
//   new_a[l] = l<32 ? a[l]    : b[l-32]
//   new_b[l] = l<32 ? a[l+32] : b[l]
static __device__ __forceinline__ void plswap(unsigned &a, unsigned &b) {
#if __has_builtin(__builtin_amdgcn_permlane32_swap)
    u32x2 r = __builtin_amdgcn_permlane32_swap((int)a, (int)b, false, false);
    a = r[0]; b = r[1];
#else
    asm volatile("v_permlane32_swap_b32 %0, %1" : "+v"(a), "+v"(b));
#endif
}

// ---------------------------------------------------------------------------
// Activations fp32 -> bf16, merged. Grid (4096, 3).
__global__ __launch_bounds__(256) void cvt3(
        const float* __restrict__ x0, const float* __restrict__ x1,
        const float* __restrict__ x2, unsigned short* __restrict__ X)
{
    const float* src = blockIdx.y == 0 ? x0 : (blockIdx.y == 1 ? x1 : x2);
    unsigned short* dst = X + (size_t)blockIdx.y * N_QKV;
    const size_t i = ((size_t)blockIdx.x * 256 + threadIdx.x) * 4;
    const float4 v = *(const float4*)(src + i);
    ushort4 s;
    s.x = f2bu(v.x); s.y = f2bu(v.y); s.z = f2bu(v.z); s.w = f2bu(v.w);
    *(ushort4*)(dst + i) = s;
}

// ---------------------------------------------------------------------------
// Wt[n][k] = bf16(W[k][n]), merged. Grid (16,16,3).
__global__ __launch_bounds__(256) void transpose_w3(
        const float* __restrict__ W0, const float* __restrict__ W1,
        const float* __restrict__ W2, unsigned short* __restrict__ Wt3)
{
    const float* W = blockIdx.z == 0 ? W0 : (blockIdx.z == 1 ? W1 : W2);
    unsigned short* Wt = Wt3 + (size_t)blockIdx.z * N_W;
    __shared__ float Ts[64][65];
    const int t = threadIdx.x;
    const int k0 = blockIdx.y * 64, n0 = blockIdx.x * 64;
#pragma unroll
    for (int i = 0; i < 16; ++i) {
        const int f = t + 256 * i, r = f >> 6, c = f & 63;
        Ts[r][c] = W[(size_t)(k0 + r) * DD + n0 + c];
    }
    __syncthreads();
#pragma unroll
    for (int i = 0; i < 16; ++i) {
        const int f = t + 256 * i, r = f >> 6, c = f & 63;
        Wt[(size_t)(n0 + r) * DD + k0 + c] = f2bu(Ts[c][r]);
    }
}

// ---------------------------------------------------------------------------
// Merged projection GEMM: z=0 Q (scale (1/8)*log2e so attn can use exp2),
// z=1 K, z=2 V^T. 128x128 tile, BK=64, scalar-register prefetch. Grid (8,32,3).
__global__ __launch_bounds__(256) void proj3(
        const unsigned short* __restrict__ X, const unsigned short* __restrict__ Wt3,
        const float* __restrict__ bq, const float* __restrict__ bk,
        const float* __restrict__ bv,
        unsigned short* __restrict__ Qp, unsigned short* __restrict__ Kp,
        unsigned short* __restrict__ Vtp)
{
    const int z = blockIdx.z;
    const unsigned short* xb = X   + (size_t)z * N_QKV;
    const unsigned short* Wt = Wt3 + (size_t)z * N_W;
    const float* bias = z == 0 ? bq : (z == 1 ? bk : bv);
    const float scale = z == 0 ? 0.18033688011112042f : 1.0f; // 0.125*log2(e)

    __shared__ unsigned short As[128][72];
    __shared__ unsigned short Bs[128][72];
    const int t = threadIdx.x, lane = t & 63, w = t >> 6;
    const int q = lane >> 4, li = lane & 15;
    const int wm = (w >> 1) * 64, wn = (w & 1) * 64;
    const int m0 = blockIdx.y * 128, n0 = blockIdx.x * 128;
    const int rs = t >> 3, cs = (t & 7) * 8;   // staging row/col

    f32x4 acc[4][4];
#pragma unroll
    for (int mt = 0; mt < 4; ++mt)
#pragma unroll
        for (int nt = 0; nt < 4; ++nt) acc[mt][nt] = (f32x4)0.f;

    uint4 pa0, pa1, pa2, pa3, pb0, pb1, pb2, pb3;
#define PROJ_LD(kk) \
    pa0 = *(const uint4*)(xb + (size_t)(m0 + rs      ) * DD + (kk) + cs); \
    pa1 = *(const uint4*)(xb + (size_t)(m0 + rs + 32 ) * DD + (kk) + cs); \
    pa2 = *(const uint4*)(xb + (size_t)(m0 + rs + 64 ) * DD + (kk) + cs); \
    pa3 = *(const uint4*)(xb + (size_t)(m0 + rs + 96 ) * DD + (kk) + cs); \
    pb0 = *(const uint4*)(Wt + (size_t)(n0 + rs      ) * DD + (kk) + cs); \
    pb1 = *(const uint4*)(Wt + (size_t)(n0 + rs + 32 ) * DD + (kk) + cs); \
    pb2 = *(const uint4*)(Wt + (size_t)(n0 + rs + 64 ) * DD + (kk) + cs); \
    pb3 = *(const uint4*)(Wt + (size_t)(n0 + rs + 96 ) * DD + (kk) + cs);

    PROJ_LD(0)

    for (int kk = 0; kk < DD; kk += 64) {
        *(uint4*)&As[rs     ][cs] = pa0;
        *(uint4*)&As[rs + 32][cs] = pa1;
        *(uint4*)&As[rs + 64][cs] = pa2;
        *(uint4*)&As[rs + 96][cs] = pa3;
        *(uint4*)&Bs[rs     ][cs] = pb0;
        *(uint4*)&Bs[rs + 32][cs] = pb1;
        *(uint4*)&Bs[rs + 64][cs] = pb2;
        *(uint4*)&Bs[rs + 96][cs] = pb3;
        __syncthreads();                       // tile visible
        if (kk + 64 < DD) { PROJ_LD(kk + 64) } // prefetch overlaps MFMA phase
#pragma unroll
        for (int ks = 0; ks < 64; ks += 32) {
            bf16x8 a[4], b[4];
#pragma unroll
            for (int mt = 0; mt < 4; ++mt) a[mt] = ldfrag(&As[wm + mt * 16 + li][ks + q * 8]);
#pragma unroll
            for (int nt = 0; nt < 4; ++nt) b[nt] = ldfrag(&Bs[wn + nt * 16 + li][ks + q * 8]);
#pragma unroll
            for (int mt = 0; mt < 4; ++mt)
#pragma unroll
                for (int nt = 0; nt < 4; ++nt)
                    acc[mt][nt] = __builtin_amdgcn_mfma_f32_16x16x32_bf16(
                        a[mt], b[nt], acc[mt][nt], 0, 0, 0);
        }
        __syncthreads();                       // reads done before overwrite
    }
#undef PROJ_LD

    float bvv[4];
#pragma unroll
    for (int nt = 0; nt < 4; ++nt) bvv[nt] = bias[n0 + wn + nt * 16 + li];

    if (z < 2) {
        unsigned short* out = z == 0 ? Qp : Kp;
#pragma unroll
        for (int mt = 0; mt < 4; ++mt)
#pragma unroll
            for (int nt = 0; nt < 4; ++nt)
#pragma unroll
                for (int reg = 0; reg < 4; ++reg) {
                    const int m = m0 + wm + mt * 16 + q * 4 + reg;
                    out[(size_t)m * DD + n0 + wn + nt * 16 + li] =
                        f2bu((acc[mt][nt][reg] + bvv[nt]) * scale);
                }
    } else {
        const int b = m0 >> 11;          // 128-row m-tiles never cross batch
        const int h = (n0 + wn) >> 6;    // 64-wide wave n-slice == one head
#pragma unroll
        for (int mt = 0; mt < 4; ++mt)
#pragma unroll
            for (int nt = 0; nt < 4; ++nt) {
                const int s = (m0 & (SS - 1)) + wm + mt * 16 + q * 4;
                const int dh = nt * 16 + li;
                ushort4 sv;
                sv.x = f2bu(acc[mt][nt][0] + bvv[nt]);
                sv.y = f2bu(acc[mt][nt][1] + bvv[nt]);
                sv.z = f2bu(acc[mt][nt][2] + bvv[nt]);
                sv.w = f2bu(acc[mt][nt][3] + bvv[nt]);
                *(ushort4*)(Vtp + ((size_t)((b * HH + h) * DHH + dh)) * SS + s) = sv;
            }
    }
}

// ---------------------------------------------------------------------------
// attn9: attn8 + {2-deep register prefetch (T4 counted vmcnt), XCD-aware grid
// decode (T1), setprio around MFMA clusters (T5)}.
//   attn8 diagnosis: all pipes <=40%, 2x waves/SIMD changed nothing, wall/
//   wave-kt 2310cy vs ~400cy issue floor -> the 2-phase stage/vmcnt-drain/
//   barrier path binds (m233 signature). Fixes:
//   - tile t's global loads live in reg-set t&1, issued at body t-2 ->
//     ds_write waits vmcnt(4) (4 newer loads outstanding), never a drain;
//     latency cover ~1.5 tiles.
//   - 1D grid decoded so each XCD owns 4 (b,h) pairs entirely: the 16
//     qt-blocks sharing a K/V head-slice land on ONE XCD's L2 -> prefetch
//     becomes L2-hit (~200cy vs ~900).
// Grid (512), 512 threads.
__global__ __launch_bounds__(512, 2) void attn9(
        const unsigned short* __restrict__ Qg, const unsigned short* __restrict__ Kg,
        const unsigned short* __restrict__ Vtg,
        const float* __restrict__ queries, float* __restrict__ outp)
{
    __shared__ unsigned short KVb[2][2][2][64][64]; // [group][K/V][dbuf][row][slot8*8] 64KB
    __shared__ float Lp[2][4][32];                  // [group][wave][q-row]

    const int t = threadIdx.x, lane = t & 63;
    const int g  = t >> 8;              // kv-half group (0: kt 0-15, 1: kt 16-31)
    const int wg = (t >> 6) & 3;        // wave-within-group = q-subtile
    const int col = lane & 31;          // q-row (QK) / dh (PV) owned by lane
    const int hi  = lane >> 5;

    // XCD-aware decode: XCD x (=bid%8) owns (b,h) pairs {x, x+8, x+16, x+24};
    // all 16 qt-blocks of a pair stay on one XCD's L2.
    const int bid = blockIdx.x;
    const int slot = bid >> 3;
    const int p = (bid & 7) + 8 * (slot >> 4);   // pair index 0..31
    const int qt = slot & 15;
    const int h = p & 15;
    const int b = p >> 4;

    const int tg = t & 255;
    const int sr = tg >> 3;             // staging row 0..31
    const int sc = tg & 7;              // staging 16B slot

    unsigned short (*Kb)[64][64] = KVb[g][0];
    unsigned short (*Vb)[64][64] = KVb[g][1];

    const unsigned short* Kbase = Kg  + (size_t)(b * SS) * DD + h * DHH;
    const unsigned short* Vbase = Vtg + ((size_t)((b * HH + h) * DHH)) * SS;

    // Q fragments: lane holds Q[q = qt*128 + wg*32 + col][d = i*16 + hi*8 + j]
    bf16x8 qa[4];
    {
        const unsigned short* qp =
            Qg + (size_t)(b * SS + qt * 128 + wg * 32 + col) * DD + h * DHH + hi * 8;
#pragma unroll
        for (int i = 0; i < 4; ++i) qa[i] = ldfrag(qp + i * 16);
    }

    f32x16 o0 = (f32x16)0.f, o1 = (f32x16)0.f;
    float lsum = 0.f;
    // two-level swizzle keys: f(row) = (row ^ (row>>3)) & 7; f(row+32)=f(row)^4
    const int xr2 = (col ^ (col >> 3)) & 7;    // read key for rows col / col+32
    const int wsw = (sr ^ (sr >> 3)) & 7;      // write key for rows sr / sr+32
    const int kvofs = g << 10;                 // group kv base (g*16 tiles * 64)

    // two register prefetch sets: tile t lives in set t&1
    uint4 aK0, aK1, aV0, aV1, bK0, bK1, bV0, bV1;
#define LD_SET(K0, K1, V0, V1, s0) \
    K0 = *(const uint4*)(Kbase + (size_t)((s0) + sr     ) * DD + sc * 8); \
    K1 = *(const uint4*)(Kbase + (size_t)((s0) + sr + 32) * DD + sc * 8); \
    V0 = *(const uint4*)(Vbase + (size_t)(sr     ) * SS + (s0) + sc * 8); \
    V1 = *(const uint4*)(Vbase + (size_t)(sr + 32) * SS + (s0) + sc * 8);

#define ST_SET(K0, K1, V0, V1, buf) \
    *(uint4*)&Kb[buf][sr     ][(sc ^ wsw) * 8]     = K0; \
    *(uint4*)&Kb[buf][sr + 32][(sc ^ wsw ^ 4) * 8] = K1; \
    *(uint4*)&Vb[buf][sr     ][(sc ^ wsw) * 8]     = V0; \
    *(uint4*)&Vb[buf][sr + 32][(sc ^ wsw ^ 4) * 8] = V1;

// one kt body; CUR/LDSET/STSET compile-time per instantiation
#define KT_BODY(CUR, LDG, STG, LDQ4, STQ4)                                    \
    {                                                                         \
        if (LDG) { LD_SET LDQ4 }                                              \
        /* QK: two independent 4-chains (k rows 0-31, 32-63) */               \
        f32x16 st0 = (f32x16)0.f, st1 = (f32x16)0.f;                          \
        __builtin_amdgcn_s_setprio(1);                                        \
        _Pragma("unroll")                                                     \
        for (int i = 0; i < 4; ++i) {                                         \
            const int sl = (i * 2 + hi) ^ xr2;                                \
            bf16x8 ka0 = ldfrag(&Kb[CUR][col     ][sl * 8]);                  \
            bf16x8 ka1 = ldfrag(&Kb[CUR][col + 32][(sl ^ 4) * 8]);            \
            st0 = __builtin_amdgcn_mfma_f32_32x32x16_bf16(ka0, qa[i], st0, 0, 0, 0); \
            st1 = __builtin_amdgcn_mfma_f32_32x32x16_bf16(ka1, qa[i], st1, 0, 0, 0); \
        }                                                                     \
        __builtin_amdgcn_s_setprio(0);                                        \
        /* P = exp2(S^T), 8-wide chunks; tree lsum */                         \
        unsigned pkw[4][4];                                                   \
        float ls = 0.f;                                                       \
        _Pragma("unroll")                                                     \
        for (int s = 0; s < 2; ++s) {                                         \
            float pe[8];                                                      \
            _Pragma("unroll")                                                 \
            for (int r = 0; r < 8; ++r) pe[r] = fexp2(st0[8 * s + r]);        \
            ls += ((pe[0] + pe[1]) + (pe[2] + pe[3])) + ((pe[4] + pe[5]) + (pe[6] + pe[7])); \
            pkw[s][0] = pkbf(pe[0], pe[1]); pkw[s][1] = pkbf(pe[2], pe[3]);   \
            pkw[s][2] = pkbf(pe[4], pe[5]); pkw[s][3] = pkbf(pe[6], pe[7]);   \
        }                                                                     \
        _Pragma("unroll")                                                     \
        for (int s = 0; s < 2; ++s) {                                         \
            float pe[8];                                                      \
            _Pragma("unroll")                                                 \
            for (int r = 0; r < 8; ++r) pe[r] = fexp2(st1[8 * s + r]);        \
            ls += ((pe[0] + pe[1]) + (pe[2] + pe[3])) + ((pe[4] + pe[5]) + (pe[6] + pe[7])); \
            pkw[2 + s][0] = pkbf(pe[0], pe[1]); pkw[2 + s][1] = pkbf(pe[2], pe[3]); \
            pkw[2 + s][2] = pkbf(pe[4], pe[5]); pkw[2 + s][3] = pkbf(pe[6], pe[7]); \
        }                                                                     \
        lsum += ls;                                                           \
        /* write tile loaded one body ago: waits vmcnt(4), not a drain */     \
        if (STG) { ST_SET STQ4 }                                              \
        /* PV: per 16-k chunk, permlane32_swap yields words 0/2 (and 1/3) */  \
        __builtin_amdgcn_s_setprio(1);                                        \
        _Pragma("unroll")                                                     \
        for (int c = 0; c < 4; ++c) {                                         \
            unsigned A0 = pkw[c][0], B0 = pkw[c][2];                          \
            unsigned A1 = pkw[c][1], B1 = pkw[c][3];                          \
            plswap(A0, B0);                                                   \
            plswap(A1, B1);                                                   \
            FragU pf;                                                         \
            pf.u.x = A0; pf.u.y = A1; pf.u.z = B0; pf.u.w = B1;               \
            const int vl = (c * 2 + hi) ^ xr2;                                \
            bf16x8 vb0 = ldfrag(&Vb[CUR][col     ][vl * 8]);                  \
            bf16x8 vb1 = ldfrag(&Vb[CUR][col + 32][(vl ^ 4) * 8]);            \
            o0 = __builtin_amdgcn_mfma_f32_32x32x16_bf16(pf.v, vb0, o0, 0, 0, 0); \
            o1 = __builtin_amdgcn_mfma_f32_32x32x16_bf16(pf.v, vb1, o1, 0, 0, 0); \
        }                                                                     \
        __builtin_amdgcn_s_setprio(0);                                        \
        __syncthreads();                                                      \
    }

    const int NT = 16;                  // tiles per group
    // prologue: tiles 0,1 in flight; tile 0 -> buf0 (waits only its own 4 loads)
    LD_SET(aK0, aK1, aV0, aV1, kvofs)
    LD_SET(bK0, bK1, bV0, bV1, kvofs + 64)
    ST_SET(aK0, aK1, aV0, aV1, 0)
    __syncthreads();

    for (int kt = 0; kt < NT; kt += 2) {
        // body kt (even, cur=0): load tile kt+2 -> set a; write tile kt+1 (set b) -> buf1
        KT_BODY(0, (kt + 2 < NT), (kt + 1 < NT),
                (aK0, aK1, aV0, aV1, kvofs + (kt + 2) * 64),
                (bK0, bK1, bV0, bV1, 1))
        // body kt+1 (odd, cur=1): load tile kt+3 -> set b; write tile kt+2 (set a) -> buf0
        KT_BODY(1, (kt + 3 < NT), (kt + 2 < NT),
                (bK0, bK1, bV0, bV1, kvofs + (kt + 3) * 64),
                (aK0, aK1, aV0, aV1, 0))
    }
#undef KT_BODY
#undef LD_SET
#undef ST_SET

    // combine the two kv-halves: pure (o,l) addition (no-max softmax)
    const float lt = lsum + __shfl_xor(lsum, 32);   // this half's full l for q-row col
    float* Ob = (float*)KVb;                        // 32KB alias on dead K/V
    const int obase = wg * 64 + lane;
    if (g == 1) {
#pragma unroll
        for (int r = 0; r < 16; ++r) {
            Ob[r * 256 + obase]        = o0[r];
            Ob[(16 + r) * 256 + obase] = o1[r];
        }
    }
    if (lane < 32) Lp[g][wg][lane] = lt;
    __syncthreads();

    if (g == 0) {
        // epilogue: rows = crow(reg,hi), cols = lane&31 (+32 for o1)
        const size_t gbase = (size_t)(b * SS + qt * 128 + wg * 32) * DD + h * DHH + col;
#pragma unroll
        for (int reg = 0; reg < 16; ++reg) {
            const int rl = (reg & 3) + 8 * (reg >> 2) + 4 * hi;
            const float li = 1.f / (Lp[0][wg][rl] + Lp[1][wg][rl]);
            const size_t gaddr = gbase + (size_t)rl * DD;
            outp[gaddr]      = (o0[reg] + Ob[reg * 256 + obase]) * li + queries[gaddr];
            outp[gaddr + 32] = (o1[reg] + Ob[(16 + reg) * 256 + obase]) * li + queries[gaddr + 32];
        }
    }
}

// ---------------------------------------------------------------------------
extern "C" void kernel_launch(void* const* d_in, const int* in_sizes, int n_in,
                              void* d_out, int out_size, void* d_ws, size_t ws_size,
                              hipStream_t stream) {
    const float* queries = (const float*)d_in[0];
    const float* keys    = (const float*)d_in[1];
    const float* values  = (const float*)d_in[2];
    const float* Wq      = (const float*)d_in[3];
    const float* bq      = (const float*)d_in[4];
    const float* Wk      = (const float*)d_in[5];
    const float* bk      = (const float*)d_in[6];
    const float* Wv      = (const float*)d_in[7];
    const float* bv      = (const float*)d_in[8];
    float* outp = (float*)d_out;

    // scratch: prefer d_ws (54 MB needed); fall back to device globals.
    const size_t need = (6 * N_QKV + 3 * N_W) * sizeof(unsigned short);
    unsigned short *Xp, *Qp, *Kp, *Vtp, *Wtp;
    if (ws_size >= need) {
        Xp  = (unsigned short*)d_ws;
        Qp  = Xp + 3 * N_QKV;
        Kp  = Qp + N_QKV;
        Vtp = Kp + N_QKV;
        Wtp = Vtp + N_QKV;
    } else {
        hipGetSymbolAddress((void**)&Xp,  HIP_SYMBOL(g_X));
        hipGetSymbolAddress((void**)&Qp,  HIP_SYMBOL(g_Q));
        hipGetSymbolAddress((void**)&Kp,  HIP_SYMBOL(g_K));
        hipGetSymbolAddress((void**)&Vtp, HIP_SYMBOL(g_Vt));
        hipGetSymbolAddress((void**)&Wtp, HIP_SYMBOL(g_Wt));
    }

    const dim3 bp(256);
    cvt3<<<dim3(MM * DD / 1024, 3), bp, 0, stream>>>(queries, keys, values, Xp);
    transpose_w3<<<dim3(16, 16, 3), bp, 0, stream>>>(Wq, Wk, Wv, Wtp);
    proj3<<<dim3(8, 32, 3), bp, 0, stream>>>(Xp, Wtp, bq, bk, bv, Qp, Kp, Vtp);
    attn9<<<dim3(512), dim3(512), 0, stream>>>(Qp, Kp, Vtp, queries, outp);
}

// Round 7
// 200.377 us; speedup vs baseline: 1.2314x; 1.0086x over previous
//
#include <hip/hip_runtime.h>
#include <hip/hip_bf16.h>
#include <math.h>

// Problem constants
#define BB 2
#define SS 2048
#define DD 1024
#define HH 16
#define DHH 64
#define MM (BB * SS) // 4096

typedef float f32x4 __attribute__((ext_vector_type(4)));
typedef float f32x16 __attribute__((ext_vector_type(16)));
typedef __bf16 bf16x8 __attribute__((ext_vector_type(8)));
typedef unsigned int u32x2 __attribute__((ext_vector_type(2)));

#define N_QKV ((size_t)MM * DD)
#define N_W   ((size_t)DD * DD)

// ---- fallback scratch (used only if ws_size is too small) -----------------
__device__ unsigned short g_X [3][N_QKV];   // bf16 activations
__device__ unsigned short g_Q [N_QKV];      // bf16 Q*0.125*log2e  [m][n]
__device__ unsigned short g_K [N_QKV];      // bf16 K        [m][n]
__device__ unsigned short g_Vt[N_QKV];      // bf16 V^T [b][h][dh][s]
__device__ unsigned short g_Wt[3][N_W];     // bf16 Wt[n][k]

// fp32 -> bf16 RNE
__device__ __forceinline__ unsigned short f2bu(float f) {
    unsigned u = __float_as_uint(f);
    unsigned r = u + 0x7FFFu + ((u >> 16) & 1u);
    return (unsigned short)(r >> 16);
}

union FragU { uint4 u; bf16x8 v; unsigned short s[8]; };
static __device__ __forceinline__ bf16x8 ldfrag(const unsigned short* p) {
    FragU f; f.u = *(const uint4*)p; return f.v;
}

// pack two f32 -> one u32 of 2xbf16 (compiler emits v_cvt_pk_bf16_f32)
static __device__ __forceinline__ unsigned pkbf(float a, float b) {
    union { __bf16 h[2]; unsigned u; } w;
    w.h[0] = (__bf16)a; w.h[1] = (__bf16)b;
    return w.u;
}

// raw v_exp_f32 (arg already in log2 domain; ocml exp2f adds range-fixup VALU)
static __device__ __forceinline__ float fexp2(float x) {
#if __has_builtin(__builtin_amdgcn_exp2f)
    return __builtin_amdgcn_exp2f(x);
#else
    float r;
    asm("v_exp_f32 %0, %1" : "=v"(r) : "v"(x));
    return r;
#endif
}

// lane[i] <-> lane[i+32] half-exchange producing BOTH PV A-frag words:
//   new_a[l] = l<32 ? a[l]    : b[l-32]
//   new_b[l] = l<32 ? a[l+32] : b[l]
static __device__ __forceinline__ void plswap(unsigned &a, unsigned &b) {
#if __has_builtin(__builtin_amdgcn_permlane32_swap)
    u32x2 r = __builtin_amdgcn_permlane32_swap((int)a, (int)b, false, false);
    a = r[0]; b = r[1];
#else
    asm volatile("v_permlane32_swap_b32 %0, %1" : "+v"(a), "+v"(b));
#endif
}

// ---------------------------------------------------------------------------
// prep3: merged {activations fp32->bf16} + {Wt[n][k] = bf16(W[k][n])}.
// Grid (4096+256, 3): bx<4096 cvt (1024 elems/block), else 64x64 transpose.
__global__ __launch_bounds__(256) void prep3(
        const float* __restrict__ x0, const float* __restrict__ x1,
        const float* __restrict__ x2, unsigned short* __restrict__ X,
        const float* __restrict__ W0, const float* __restrict__ W1,
        const float* __restrict__ W2, unsigned short* __restrict__ Wt3)
{
    __shared__ float Ts[64][65];
    const int z = blockIdx.y, t = threadIdx.x;
    if (blockIdx.x < 4096) {
        const float* src = z == 0 ? x0 : (z == 1 ? x1 : x2);
        unsigned short* dst = X + (size_t)z * N_QKV;
        const size_t i = ((size_t)blockIdx.x * 256 + t) * 4;
        const float4 v = *(const float4*)(src + i);
        ushort4 s;
        s.x = f2bu(v.x); s.y = f2bu(v.y); s.z = f2bu(v.z); s.w = f2bu(v.w);
        *(ushort4*)(dst + i) = s;
    } else {
        const float* W = z == 0 ? W0 : (z == 1 ? W1 : W2);
        unsigned short* Wt = Wt3 + (size_t)z * N_W;
        const int bx = blockIdx.x - 4096;
        const int k0 = (bx >> 4) * 64, n0 = (bx & 15) * 64;
#pragma unroll
        for (int i = 0; i < 16; ++i) {
            const int f = t + 256 * i, r = f >> 6, c = f & 63;
            Ts[r][c] = W[(size_t)(k0 + r) * DD + n0 + c];
        }
        __syncthreads();
#pragma unroll
        for (int i = 0; i < 16; ++i) {
            const int f = t + 256 * i, r = f >> 6, c = f & 63;
            Wt[(size_t)(n0 + r) * DD + k0 + c] = f2bu(Ts[c][r]);
        }
    }
}

// ---------------------------------------------------------------------------
// Merged projection GEMM: z=0 Q (scale (1/8)*log2e so attn can use exp2),
// z=1 K, z=2 V^T. 128x128 tile, BK=64, scalar-register prefetch. Grid (8,32,3).
__global__ __launch_bounds__(256) void proj3(
        const unsigned short* __restrict__ X, const unsigned short* __restrict__ Wt3,
        const float* __restrict__ bq, const float* __restrict__ bk,
        const float* __restrict__ bv,
        unsigned short* __restrict__ Qp, unsigned short* __restrict__ Kp,
        unsigned short* __restrict__ Vtp)
{
    const int z = blockIdx.z;
    const unsigned short* xb = X   + (size_t)z * N_QKV;
    const unsigned short* Wt = Wt3 + (size_t)z * N_W;
    const float* bias = z == 0 ? bq : (z == 1 ? bk : bv);
    const float scale = z == 0 ? 0.18033688011112042f : 1.0f; // 0.125*log2(e)

    __shared__ unsigned short As[128][72];
    __shared__ unsigned short Bs[128][72];
    const int t = threadIdx.x, lane = t & 63, w = t >> 6;
    const int q = lane >> 4, li = lane & 15;
    const int wm = (w >> 1) * 64, wn = (w & 1) * 64;
    const int m0 = blockIdx.y * 128, n0 = blockIdx.x * 128;
    const int rs = t >> 3, cs = (t & 7) * 8;   // staging row/col

    f32x4 acc[4][4];
#pragma unroll
    for (int mt = 0; mt < 4; ++mt)
#pragma unroll
        for (int nt = 0; nt < 4; ++nt) acc[mt][nt] = (f32x4)0.f;

    uint4 pa0, pa1, pa2, pa3, pb0, pb1, pb2, pb3;
#define PROJ_LD(kk) \
    pa0 = *(const uint4*)(xb + (size_t)(m0 + rs      ) * DD + (kk) + cs); \
    pa1 = *(const uint4*)(xb + (size_t)(m0 + rs + 32 ) * DD + (kk) + cs); \
    pa2 = *(const uint4*)(xb + (size_t)(m0 + rs + 64 ) * DD + (kk) + cs); \
    pa3 = *(const uint4*)(xb + (size_t)(m0 + rs + 96 ) * DD + (kk) + cs); \
    pb0 = *(const uint4*)(Wt + (size_t)(n0 + rs      ) * DD + (kk) + cs); \
    pb1 = *(const uint4*)(Wt + (size_t)(n0 + rs + 32 ) * DD + (kk) + cs); \
    pb2 = *(const uint4*)(Wt + (size_t)(n0 + rs + 64 ) * DD + (kk) + cs); \
    pb3 = *(const uint4*)(Wt + (size_t)(n0 + rs + 96 ) * DD + (kk) + cs);

    PROJ_LD(0)

    for (int kk = 0; kk < DD; kk += 64) {
        *(uint4*)&As[rs     ][cs] = pa0;
        *(uint4*)&As[rs + 32][cs] = pa1;
        *(uint4*)&As[rs + 64][cs] = pa2;
        *(uint4*)&As[rs + 96][cs] = pa3;
        *(uint4*)&Bs[rs     ][cs] = pb0;
        *(uint4*)&Bs[rs + 32][cs] = pb1;
        *(uint4*)&Bs[rs + 64][cs] = pb2;
        *(uint4*)&Bs[rs + 96][cs] = pb3;
        __syncthreads();                       // tile visible
        if (kk + 64 < DD) { PROJ_LD(kk + 64) } // prefetch overlaps MFMA phase
#pragma unroll
        for (int ks = 0; ks < 64; ks += 32) {
            bf16x8 a[4], b[4];
#pragma unroll
            for (int mt = 0; mt < 4; ++mt) a[mt] = ldfrag(&As[wm + mt * 16 + li][ks + q * 8]);
#pragma unroll
            for (int nt = 0; nt < 4; ++nt) b[nt] = ldfrag(&Bs[wn + nt * 16 + li][ks + q * 8]);
#pragma unroll
            for (int mt = 0; mt < 4; ++mt)
#pragma unroll
                for (int nt = 0; nt < 4; ++nt)
                    acc[mt][nt] = __builtin_amdgcn_mfma_f32_16x16x32_bf16(
                        a[mt], b[nt], acc[mt][nt], 0, 0, 0);
        }
        __syncthreads();                       // reads done before overwrite
    }
#undef PROJ_LD

    float bvv[4];
#pragma unroll
    for (int nt = 0; nt < 4; ++nt) bvv[nt] = bias[n0 + wn + nt * 16 + li];

    if (z < 2) {
        unsigned short* out = z == 0 ? Qp : Kp;
#pragma unroll
        for (int mt = 0; mt < 4; ++mt)
#pragma unroll
            for (int nt = 0; nt < 4; ++nt)
#pragma unroll
                for (int reg = 0; reg < 4; ++reg) {
                    const int m = m0 + wm + mt * 16 + q * 4 + reg;
                    out[(size_t)m * DD + n0 + wn + nt * 16 + li] =
                        f2bu((acc[mt][nt][reg] + bvv[nt]) * scale);
                }
    } else {
        const int b = m0 >> 11;          // 128-row m-tiles never cross batch
        const int h = (n0 + wn) >> 6;    // 64-wide wave n-slice == one head
#pragma unroll
        for (int mt = 0; mt < 4; ++mt)
#pragma unroll
            for (int nt = 0; nt < 4; ++nt) {
                const int s = (m0 & (SS - 1)) + wm + mt * 16 + q * 4;
                const int dh = nt * 16 + li;
                ushort4 sv;
                sv.x = f2bu(acc[mt][nt][0] + bvv[nt]);
                sv.y = f2bu(acc[mt][nt][1] + bvv[nt]);
                sv.z = f2bu(acc[mt][nt][2] + bvv[nt]);
                sv.w = f2bu(acc[mt][nt][3] + bvv[nt]);
                *(ushort4*)(Vtp + ((size_t)((b * HH + h) * DHH + dh)) * SS + s) = sv;
            }
    }
}

// ---------------------------------------------------------------------------
// attn10: attn9 + T15 software pipeline (PV shifted one tile).
//   attn9 diagnosis: pipes all <=45%, wall/body ~8.5k cy vs ~1k critical path
//   -> barrier-lockstep on the serial QK->exp->PV chain binds. Restructure:
//     body t: LD(t+2); [QK(t) || PV(t-1)] interleaved MFMA cluster;
//             barrier; ST(t+1); exp(t)->pkw; barrier
//   - QK(t) and PV(t-1) are independent -> 4 interleaved MFMA chains
//   - exp(t) consumed only next body -> its latency hides under the next
//     MFMA cluster, and it covers ST's ds_write drain before barrier2
//   - V-parity: PV(t-1) reads Vb[(t-1)&1]; ST(t+1) writes same parity ->
//     barrier1 between them keeps it safe with 2 buffers
//   Cost: 2nd live pkw set (+16 VGPR), one extra barrier/body, extra
//   barrier before the Ob alias (PV(15) runs after the loop).
// Grid (512), 512 threads.
__global__ __launch_bounds__(512, 2) void attn10(
        const unsigned short* __restrict__ Qg, const unsigned short* __restrict__ Kg,
        const unsigned short* __restrict__ Vtg,
        const float* __restrict__ queries, float* __restrict__ outp)
{
    __shared__ unsigned short KVb[2][2][2][64][64]; // [group][K/V][dbuf][row][slot8*8] 64KB
    __shared__ float Lp[2][4][32];                  // [group][wave][q-row]

    const int t = threadIdx.x, lane = t & 63;
    const int g  = t >> 8;              // kv-half group (0: kt 0-15, 1: kt 16-31)
    const int wg = (t >> 6) & 3;        // wave-within-group = q-subtile
    const int col = lane & 31;          // q-row (QK) / dh (PV) owned by lane
    const int hi  = lane >> 5;

    // XCD-aware decode: XCD x (=bid%8) owns (b,h) pairs {x, x+8, x+16, x+24};
    // all 16 qt-blocks of a pair stay on one XCD's L2.
    const int bid = blockIdx.x;
    const int slot = bid >> 3;
    const int p = (bid & 7) + 8 * (slot >> 4);   // pair index 0..31
    const int qt = slot & 15;
    const int h = p & 15;
    const int b = p >> 4;

    const int tg = t & 255;
    const int sr = tg >> 3;             // staging row 0..31
    const int sc = tg & 7;              // staging 16B slot

    unsigned short (*Kb)[64][64] = KVb[g][0];
    unsigned short (*Vb)[64][64] = KVb[g][1];

    const unsigned short* Kbase = Kg  + (size_t)(b * SS) * DD + h * DHH;
    const unsigned short* Vbase = Vtg + ((size_t)((b * HH + h) * DHH)) * SS;

    // Q fragments: lane holds Q[q = qt*128 + wg*32 + col][d = i*16 + hi*8 + j]
    bf16x8 qa[4];
    {
        const unsigned short* qp =
            Qg + (size_t)(b * SS + qt * 128 + wg * 32 + col) * DD + h * DHH + hi * 8;
#pragma unroll
        for (int i = 0; i < 4; ++i) qa[i] = ldfrag(qp + i * 16);
    }

    f32x16 o0 = (f32x16)0.f, o1 = (f32x16)0.f;
    float lsum = 0.f;
    // two-level swizzle keys: f(row) = (row ^ (row>>3)) & 7; f(row+32)=f(row)^4
    const int xr2 = (col ^ (col >> 3)) & 7;    // read key for rows col / col+32
    const int wsw = (sr ^ (sr >> 3)) & 7;      // write key for rows sr / sr+32
    const int kvofs = g << 10;                 // group kv base (g*16 tiles * 64)

    // two register prefetch sets: tile t lives in set t&1
    uint4 aK0, aK1, aV0, aV1, bK0, bK1, bV0, bV1;
    unsigned pkwE[4][4], pkwO[4][4];   // exp/pack result of even / odd bodies

#define LD_SET(K0, K1, V0, V1, s0) \
    K0 = *(const uint4*)(Kbase + (size_t)((s0) + sr     ) * DD + sc * 8); \
    K1 = *(const uint4*)(Kbase + (size_t)((s0) + sr + 32) * DD + sc * 8); \
    V0 = *(const uint4*)(Vbase + (size_t)(sr     ) * SS + (s0) + sc * 8); \
    V1 = *(const uint4*)(Vbase + (size_t)(sr + 32) * SS + (s0) + sc * 8);

#define ST_SET(K0, K1, V0, V1, buf) \
    *(uint4*)&Kb[buf][sr     ][(sc ^ wsw) * 8]     = K0; \
    *(uint4*)&Kb[buf][sr + 32][(sc ^ wsw ^ 4) * 8] = K1; \
    *(uint4*)&Vb[buf][sr     ][(sc ^ wsw) * 8]     = V0; \
    *(uint4*)&Vb[buf][sr + 32][(sc ^ wsw ^ 4) * 8] = V1;

// body t (parity CUR): LD(t+2); [QK(t) || PV(t-1)]; bar; ST(t+1); exp->PKW_C; bar
#define BODY(CUR, PKW_C, PKW_P, DO_PREV, LDG, LDQ, STG, STQ)                  \
    {                                                                         \
        if (LDG) { LD_SET LDQ }                                               \
        FragU pf[4];                                                          \
        if (DO_PREV) {                                                        \
            _Pragma("unroll")                                                 \
            for (int c = 0; c < 4; ++c) {                                     \
                unsigned A0 = PKW_P[c][0], B0 = PKW_P[c][2];                  \
                unsigned A1 = PKW_P[c][1], B1 = PKW_P[c][3];                  \
                plswap(A0, B0); plswap(A1, B1);                               \
                pf[c].u.x = A0; pf[c].u.y = A1; pf[c].u.z = B0; pf[c].u.w = B1; \
            }                                                                 \
        }                                                                     \
        f32x16 st0 = (f32x16)0.f, st1 = (f32x16)0.f;                          \
        __builtin_amdgcn_s_setprio(1);                                        \
        _Pragma("unroll")                                                     \
        for (int i = 0; i < 4; ++i) {                                         \
            const int sl = (i * 2 + hi) ^ xr2;                                \
            bf16x8 ka0 = ldfrag(&Kb[CUR][col     ][sl * 8]);                  \
            bf16x8 ka1 = ldfrag(&Kb[CUR][col + 32][(sl ^ 4) * 8]);            \
            st0 = __builtin_amdgcn_mfma_f32_32x32x16_bf16(ka0, qa[i], st0, 0, 0, 0); \
            st1 = __builtin_amdgcn_mfma_f32_32x32x16_bf16(ka1, qa[i], st1, 0, 0, 0); \
            if (DO_PREV) {                                                    \
                bf16x8 vb0 = ldfrag(&Vb[(CUR) ^ 1][col     ][sl * 8]);        \
                bf16x8 vb1 = ldfrag(&Vb[(CUR) ^ 1][col + 32][(sl ^ 4) * 8]);  \
                o0 = __builtin_amdgcn_mfma_f32_32x32x16_bf16(pf[i].v, vb0, o0, 0, 0, 0); \
                o1 = __builtin_amdgcn_mfma_f32_32x32x16_bf16(pf[i].v, vb1, o1, 0, 0, 0); \
            }                                                                 \
        }                                                                     \
        __builtin_amdgcn_s_setprio(0);                                        \
        __syncthreads();   /* all LDS reads of this body done */              \
        if (STG) { ST_SET STQ }  /* waits vmcnt(4): loads aged 1 body */      \
        /* exp(t) -> PKW_C: consumed next body; covers ST drain */            \
        float ls = 0.f;                                                       \
        _Pragma("unroll")                                                     \
        for (int s = 0; s < 2; ++s) {                                         \
            float pe[8];                                                      \
            _Pragma("unroll")                                                 \
            for (int r = 0; r < 8; ++r) pe[r] = fexp2(st0[8 * s + r]);        \
            ls += ((pe[0] + pe[1]) + (pe[2] + pe[3])) + ((pe[4] + pe[5]) + (pe[6] + pe[7])); \
            PKW_C[s][0] = pkbf(pe[0], pe[1]); PKW_C[s][1] = pkbf(pe[2], pe[3]); \
            PKW_C[s][2] = pkbf(pe[4], pe[5]); PKW_C[s][3] = pkbf(pe[6], pe[7]); \
        }                                                                     \
        _Pragma("unroll")                                                     \
        for (int s = 0; s < 2; ++s) {                                         \
            float pe[8];                                                      \
            _Pragma("unroll")                                                 \
            for (int r = 0; r < 8; ++r) pe[r] = fexp2(st1[8 * s + r]);        \
            ls += ((pe[0] + pe[1]) + (pe[2] + pe[3])) + ((pe[4] + pe[5]) + (pe[6] + pe[7])); \
            PKW_C[2 + s][0] = pkbf(pe[0], pe[1]); PKW_C[2 + s][1] = pkbf(pe[2], pe[3]); \
            PKW_C[2 + s][2] = pkbf(pe[4], pe[5]); PKW_C[2 + s][3] = pkbf(pe[6], pe[7]); \
        }                                                                     \
        lsum += ls;                                                           \
        __syncthreads();   /* next tile staged + visible */                   \
    }

    const int NT = 16;                  // tiles per group
    // prologue: tiles 0,1 in flight; tile 0 -> buf0
    LD_SET(aK0, aK1, aV0, aV1, kvofs)
    LD_SET(bK0, bK1, bV0, bV1, kvofs + 64)
    ST_SET(aK0, aK1, aV0, aV1, 0)
    __syncthreads();

    // body 0 (even): QK(0) only; LD(2)->a; ST(1)->buf1; exp(0)->pkwE
    BODY(0, pkwE, pkwO, false, true, (aK0, aK1, aV0, aV1, kvofs + 128),
         true, (bK0, bK1, bV0, bV1, 1))

    // bodies (1,2), (3,4), ..., (13,14)
    for (int kt = 1; kt <= 13; kt += 2) {
        // odd body kt: QK(kt)+PV(kt-1); LD(kt+2)->b; ST(kt+1)->buf0; exp->pkwO
        BODY(1, pkwO, pkwE, true, true, (bK0, bK1, bV0, bV1, kvofs + (kt + 2) * 64),
             true, (aK0, aK1, aV0, aV1, 0))
        // even body kt+1: QK(kt+1)+PV(kt); LD(kt+3)->a; ST(kt+2)->buf1; exp->pkwE
        BODY(0, pkwE, pkwO, true, (kt + 3 < NT),
             (aK0, aK1, aV0, aV1, kvofs + (kt + 3) * 64),
             true, (bK0, bK1, bV0, bV1, 1))
    }
    // body 15 (odd): QK(15)+PV(14); no LD/ST; exp(15)->pkwO
    BODY(1, pkwO, pkwE, true, false, (bK0, bK1, bV0, bV1, 0),
         false, (aK0, aK1, aV0, aV1, 0))

    // epilogue PV(15): pkwO, Vb[1] (no further writes)
    {
#pragma unroll
        for (int c = 0; c < 4; ++c) {
            unsigned A0 = pkwO[c][0], B0 = pkwO[c][2];
            unsigned A1 = pkwO[c][1], B1 = pkwO[c][3];
            plswap(A0, B0); plswap(A1, B1);
            FragU pf;
            pf.u.x = A0; pf.u.y = A1; pf.u.z = B0; pf.u.w = B1;
            const int sl = (c * 2 + hi) ^ xr2;
            bf16x8 vb0 = ldfrag(&Vb[1][col     ][sl * 8]);
            bf16x8 vb1 = ldfrag(&Vb[1][col + 32][(sl ^ 4) * 8]);
            o0 = __builtin_amdgcn_mfma_f32_32x32x16_bf16(pf.v, vb0, o0, 0, 0, 0);
            o1 = __builtin_amdgcn_mfma_f32_32x32x16_bf16(pf.v, vb1, o1, 0, 0, 0);
        }
    }
    __syncthreads();                    // all V reads done before Ob alias
#undef BODY
#undef LD_SET
#undef ST_SET

    // combine the two kv-halves: pure (o,l) addition (no-max softmax)
    const float lt = lsum + __shfl_xor(lsum, 32);   // this half's full l for q-row col
    float* Ob = (float*)KVb;                        // 32KB alias on dead K/V
    const int obase = wg * 64 + lane;
    if (g == 1) {
#pragma unroll
        for (int r = 0; r < 16; ++r) {
            Ob[r * 256 + obase]        = o0[r];
            Ob[(16 + r) * 256 + obase] = o1[r];
        }
    }
    if (lane < 32) Lp[g][wg][lane] = lt;
    __syncthreads();

    if (g == 0) {
        // epilogue: rows = crow(reg,hi), cols = lane&31 (+32 for o1)
        const size_t gbase = (size_t)(b * SS + qt * 128 + wg * 32) * DD + h * DHH + col;
#pragma unroll
        for (int reg = 0; reg < 16; ++reg) {
            const int rl = (reg & 3) + 8 * (reg >> 2) + 4 * hi;
            const float li = 1.f / (Lp[0][wg][rl] + Lp[1][wg][rl]);
            const size_t gaddr = gbase + (size_t)rl * DD;
            outp[gaddr]      = (o0[reg] + Ob[reg * 256 + obase]) * li + queries[gaddr];
            outp[gaddr + 32] = (o1[reg] + Ob[(16 + reg) * 256 + obase]) * li + queries[gaddr + 32];
        }
    }
}

// ---------------------------------------------------------------------------
extern "C" void kernel_launch(void* const* d_in, const int* in_sizes, int n_in,
                              void* d_out, int out_size, void* d_ws, size_t ws_size,
                              hipStream_t stream) {
    const float* queries = (const float*)d_in[0];
    const float* keys    = (const float*)d_in[1];
    const float* values  = (const float*)d_in[2];
    const float* Wq      = (const float*)d_in[3];
    const float* bq      = (const float*)d_in[4];
    const float* Wk      = (const float*)d_in[5];
    const float* bk      = (const float*)d_in[6];
    const float* Wv      = (const float*)d_in[7];
    const float* bv      = (const float*)d_in[8];
    float* outp = (float*)d_out;

    // scratch: prefer d_ws (54 MB needed); fall back to device globals.
    const size_t need = (6 * N_QKV + 3 * N_W) * sizeof(unsigned short);
    unsigned short *Xp, *Qp, *Kp, *Vtp, *Wtp;
    if (ws_size >= need) {
        Xp  = (unsigned short*)d_ws;
        Qp  = Xp + 3 * N_QKV;
        Kp  = Qp + N_QKV;
        Vtp = Kp + N_QKV;
        Wtp = Vtp + N_QKV;
    } else {
        hipGetSymbolAddress((void**)&Xp,  HIP_SYMBOL(g_X));
        hipGetSymbolAddress((void**)&Qp,  HIP_SYMBOL(g_Q));
        hipGetSymbolAddress((void**)&Kp,  HIP_SYMBOL(g_K));
        hipGetSymbolAddress((void**)&Vtp, HIP_SYMBOL(g_Vt));
        hipGetSymbolAddress((void**)&Wtp, HIP_SYMBOL(g_Wt));
    }

    const dim3 bp(256);
    prep3<<<dim3(4096 + 256, 3), bp, 0, stream>>>(queries, keys, values, Xp,
                                                  Wq, Wk, Wv, Wtp);
    proj3<<<dim3(8, 32, 3), bp, 0, stream>>>(Xp, Wtp, bq, bk, bv, Qp, Kp, Vtp);
    attn10<<<dim3(512), dim3(512), 0, stream>>>(Qp, Kp, Vtp, queries, outp);
}

// Round 8
// 193.457 us; speedup vs baseline: 1.2754x; 1.0358x over previous
//
#include <hip/hip_runtime.h>
#include <hip/hip_bf16.h>
#include <math.h>

// Problem constants
#define BB 2
#define SS 2048
#define DD 1024
#define HH 16
#define DHH 64
#define MM (BB * SS) // 4096

typedef float f32x4 __attribute__((ext_vector_type(4)));
typedef float f32x16 __attribute__((ext_vector_type(16)));
typedef __bf16 bf16x8 __attribute__((ext_vector_type(8)));
typedef unsigned int u32x2 __attribute__((ext_vector_type(2)));

#define N_QKV ((size_t)MM * DD)
#define N_W   ((size_t)DD * DD)

// ---- fallback scratch (used only if ws_size is too small) -----------------
__device__ unsigned short g_X [3][N_QKV];   // bf16 activations
__device__ unsigned short g_Q [N_QKV];      // bf16 Q*0.125*log2e  [m][n]
__device__ unsigned short g_K [N_QKV];      // bf16 K        [m][n]
__device__ unsigned short g_Vt[N_QKV];      // bf16 V^T [b][h][dh][s]
__device__ unsigned short g_Wt[3][N_W];     // bf16 Wt[n][k]

// fp32 -> bf16 RNE
__device__ __forceinline__ unsigned short f2bu(float f) {
    unsigned u = __float_as_uint(f);
    unsigned r = u + 0x7FFFu + ((u >> 16) & 1u);
    return (unsigned short)(r >> 16);
}

union FragU { uint4 u; bf16x8 v; unsigned short s[8]; };
static __device__ __forceinline__ bf16x8 ldfrag(const unsigned short* p) {
    FragU f; f.u = *(const uint4*)p; return f.v;
}

// pack two f32 -> one u32 of 2xbf16 (compiler emits v_cvt_pk_bf16_f32)
static __device__ __forceinline__ unsigned pkbf(float a, float b) {
    union { __bf16 h[2]; unsigned u; } w;
    w.h[0] = (__bf16)a; w.h[1] = (__bf16)b;
    return w.u;
}

// raw v_exp_f32 (arg already in log2 domain; ocml exp2f adds range-fixup VALU)
static __device__ __forceinline__ float fexp2(float x) {
#if __has_builtin(__builtin_amdgcn_exp2f)
    return __builtin_amdgcn_exp2f(x);
#else
    float r;
    asm("v_exp_f32 %0, %1" : "=v"(r) : "v"(x));
    return r;
#endif
}

// lane[i] <-> lane[i+32] half-exchange producing BOTH PV A-frag words:
//   new_a[l] = l<32 ? a[l]    : b[l-32]
//   new_b[l] = l<32 ? a[l+32] : b[l]
static __device__ __forceinline__ void plswap(unsigned &a, unsigned &b) {
#if __has_builtin(__builtin_amdgcn_permlane32_swap)
    u32x2 r = __builtin_amdgcn_permlane32_swap((int)a, (int)b, false, false);
    a = r[0]; b = r[1];
#else
    asm volatile("v_permlane32_swap_b32 %0, %1" : "+v"(a), "+v"(b));
#endif
}

// ---------------------------------------------------------------------------
// prep3: merged {activations fp32->bf16} + {Wt[n][k] = bf16(W[k][n])}.
// Grid (4096+256, 3): bx<4096 cvt (1024 elems/block), else 64x64 transpose.
__global__ __launch_bounds__(256) void prep3(
        const float* __restrict__ x0, const float* __restrict__ x1,
        const float* __restrict__ x2, unsigned short* __restrict__ X,
        const float* __restrict__ W0, const float* __restrict__ W1,
        const float* __restrict__ W2, unsigned short* __restrict__ Wt3)
{
    __shared__ float Ts[64][65];
    const int z = blockIdx.y, t = threadIdx.x;
    if (blockIdx.x < 4096) {
        const float* src = z == 0 ? x0 : (z == 1 ? x1 : x2);
        unsigned short* dst = X + (size_t)z * N_QKV;
        const size_t i = ((size_t)blockIdx.x * 256 + t) * 4;
        const float4 v = *(const float4*)(src + i);
        ushort4 s;
        s.x = f2bu(v.x); s.y = f2bu(v.y); s.z = f2bu(v.z); s.w = f2bu(v.w);
        *(ushort4*)(dst + i) = s;
    } else {
        const float* W = z == 0 ? W0 : (z == 1 ? W1 : W2);
        unsigned short* Wt = Wt3 + (size_t)z * N_W;
        const int bx = blockIdx.x - 4096;
        const int k0 = (bx >> 4) * 64, n0 = (bx & 15) * 64;
#pragma unroll
        for (int i = 0; i < 16; ++i) {
            const int f = t + 256 * i, r = f >> 6, c = f & 63;
            Ts[r][c] = W[(size_t)(k0 + r) * DD + n0 + c];
        }
        __syncthreads();
#pragma unroll
        for (int i = 0; i < 16; ++i) {
            const int f = t + 256 * i, r = f >> 6, c = f & 63;
            Wt[(size_t)(n0 + r) * DD + k0 + c] = f2bu(Ts[c][r]);
        }
    }
}

// ---------------------------------------------------------------------------
// Merged projection GEMM: z=0 Q (scale (1/8)*log2e so attn can use exp2),
// z=1 K, z=2 V^T. 128x128 tile, BK=64, scalar-register prefetch.
// 1D grid 768 with XCD-aware decode (T1): the 8 n-blocks sharing one
// (z, m-panel) land on ONE XCD -> A-panel fetched once per XCD L2 (default
// round-robin fetched it on all 8).
__global__ __launch_bounds__(256) void proj3(
        const unsigned short* __restrict__ X, const unsigned short* __restrict__ Wt3,
        const float* __restrict__ bq, const float* __restrict__ bk,
        const float* __restrict__ bv,
        unsigned short* __restrict__ Qp, unsigned short* __restrict__ Kp,
        unsigned short* __restrict__ Vtp)
{
    // decode: x = XCD, zm = (z,m) pair; each XCD owns 12 zm x 8 n = 96 blocks
    const int bid = blockIdx.x;
    const int xx = bid & 7, j = bid >> 3;      // j 0..95
    const int zm = xx * 12 + (j >> 3);         // 0..95
    const int z  = zm >> 5;                    // 0..2
    const int m0 = (zm & 31) * 128;
    const int n0 = (j & 7) * 128;

    const unsigned short* xb = X   + (size_t)z * N_QKV;
    const unsigned short* Wt = Wt3 + (size_t)z * N_W;
    const float* bias = z == 0 ? bq : (z == 1 ? bk : bv);
    const float scale = z == 0 ? 0.18033688011112042f : 1.0f; // 0.125*log2(e)

    __shared__ unsigned short As[128][72];
    __shared__ unsigned short Bs[128][72];
    const int t = threadIdx.x, lane = t & 63, w = t >> 6;
    const int q = lane >> 4, li = lane & 15;
    const int wm = (w >> 1) * 64, wn = (w & 1) * 64;
    const int rs = t >> 3, cs = (t & 7) * 8;   // staging row/col

    f32x4 acc[4][4];
#pragma unroll
    for (int mt = 0; mt < 4; ++mt)
#pragma unroll
        for (int nt = 0; nt < 4; ++nt) acc[mt][nt] = (f32x4)0.f;

    uint4 pa0, pa1, pa2, pa3, pb0, pb1, pb2, pb3;
#define PROJ_LD(kk) \
    pa0 = *(const uint4*)(xb + (size_t)(m0 + rs      ) * DD + (kk) + cs); \
    pa1 = *(const uint4*)(xb + (size_t)(m0 + rs + 32 ) * DD + (kk) + cs); \
    pa2 = *(const uint4*)(xb + (size_t)(m0 + rs + 64 ) * DD + (kk) + cs); \
    pa3 = *(const uint4*)(xb + (size_t)(m0 + rs + 96 ) * DD + (kk) + cs); \
    pb0 = *(const uint4*)(Wt + (size_t)(n0 + rs      ) * DD + (kk) + cs); \
    pb1 = *(const uint4*)(Wt + (size_t)(n0 + rs + 32 ) * DD + (kk) + cs); \
    pb2 = *(const uint4*)(Wt + (size_t)(n0 + rs + 64 ) * DD + (kk) + cs); \
    pb3 = *(const uint4*)(Wt + (size_t)(n0 + rs + 96 ) * DD + (kk) + cs);

    PROJ_LD(0)

    for (int kk = 0; kk < DD; kk += 64) {
        *(uint4*)&As[rs     ][cs] = pa0;
        *(uint4*)&As[rs + 32][cs] = pa1;
        *(uint4*)&As[rs + 64][cs] = pa2;
        *(uint4*)&As[rs + 96][cs] = pa3;
        *(uint4*)&Bs[rs     ][cs] = pb0;
        *(uint4*)&Bs[rs + 32][cs] = pb1;
        *(uint4*)&Bs[rs + 64][cs] = pb2;
        *(uint4*)&Bs[rs + 96][cs] = pb3;
        __syncthreads();                       // tile visible
        if (kk + 64 < DD) { PROJ_LD(kk + 64) } // prefetch overlaps MFMA phase
#pragma unroll
        for (int ks = 0; ks < 64; ks += 32) {
            bf16x8 a[4], b[4];
#pragma unroll
            for (int mt = 0; mt < 4; ++mt) a[mt] = ldfrag(&As[wm + mt * 16 + li][ks + q * 8]);
#pragma unroll
            for (int nt = 0; nt < 4; ++nt) b[nt] = ldfrag(&Bs[wn + nt * 16 + li][ks + q * 8]);
#pragma unroll
            for (int mt = 0; mt < 4; ++mt)
#pragma unroll
                for (int nt = 0; nt < 4; ++nt)
                    acc[mt][nt] = __builtin_amdgcn_mfma_f32_16x16x32_bf16(
                        a[mt], b[nt], acc[mt][nt], 0, 0, 0);
        }
        __syncthreads();                       // reads done before overwrite
    }
#undef PROJ_LD

    float bvv[4];
#pragma unroll
    for (int nt = 0; nt < 4; ++nt) bvv[nt] = bias[n0 + wn + nt * 16 + li];

    if (z < 2) {
        unsigned short* out = z == 0 ? Qp : Kp;
#pragma unroll
        for (int mt = 0; mt < 4; ++mt)
#pragma unroll
            for (int nt = 0; nt < 4; ++nt)
#pragma unroll
                for (int reg = 0; reg < 4; ++reg) {
                    const int m = m0 + wm + mt * 16 + q * 4 + reg;
                    out[(size_t)m * DD + n0 + wn + nt * 16 + li] =
                        f2bu((acc[mt][nt][reg] + bvv[nt]) * scale);
                }
    } else {
        const int b = m0 >> 11;          // 128-row m-tiles never cross batch
        const int h = (n0 + wn) >> 6;    // 64-wide wave n-slice == one head
#pragma unroll
        for (int mt = 0; mt < 4; ++mt)
#pragma unroll
            for (int nt = 0; nt < 4; ++nt) {
                const int s = (m0 & (SS - 1)) + wm + mt * 16 + q * 4;
                const int dh = nt * 16 + li;
                ushort4 sv;
                sv.x = f2bu(acc[mt][nt][0] + bvv[nt]);
                sv.y = f2bu(acc[mt][nt][1] + bvv[nt]);
                sv.z = f2bu(acc[mt][nt][2] + bvv[nt]);
                sv.w = f2bu(acc[mt][nt][3] + bvv[nt]);
                *(ushort4*)(Vtp + ((size_t)((b * HH + h) * DHH + dh)) * SS + s) = sv;
            }
    }
}

// ---------------------------------------------------------------------------
// attn11: 256 q-rows/block, 8 waves, ONE shared KV stream, quad-buffered.
//   Diagnosis: 6 variants stuck 57-62us; no pipe >45%. Unattacked axis:
//   staged-byte reuse. attn9 staged each K/V tile for 128 q-rows (4 waves/
//   group, 2 groups + 2 blocks duplicating the stream per CU). Here ONE
//   stream serves 8 waves (256 q-rows): global loads, ds_writes, and
//   stage-wait rounds per MFMA halve.
//   - quad-buffer (4 x 8KB x {K,V} = 64KB): body computes 2 tiles (128k,
//     bufs p,p+1) with ONE barrier while storing the next 2 tiles (bufs
//     p+2,p+3) mid-body; LD->ds_write distance = a full body.
//   - 16 barrier-rounds total (vs attn9's 16 per 64k-pair... now per 128k).
//   - grid 256 = 1 block/CU; XCD decode: XCD owns 4 (b,h) pairs entirely.
//   - launch_bounds(512,1): cap 256 VGPR (need ~160); 2 waves/SIMD is
//     enough (attn8 showed 4/SIMD buys nothing). WRITE_SIZE = spill tripwire.
// Grid (256), 512 threads.
__global__ __launch_bounds__(512, 1) void attn11(
        const unsigned short* __restrict__ Qg, const unsigned short* __restrict__ Kg,
        const unsigned short* __restrict__ Vtg,
        const float* __restrict__ queries, float* __restrict__ outp)
{
    __shared__ unsigned short Kb[4][64][64];   // 32KB
    __shared__ unsigned short Vb[4][64][64];   // 32KB
    __shared__ float Lp[8][32];                // 1KB

    const int t = threadIdx.x, lane = t & 63, w = t >> 6;   // w 0..7
    const int col = lane & 31;          // q-row (QK) / dh (PV) owned by lane
    const int hi  = lane >> 5;

    // XCD decode: x = bid&7 owns (b,h) pairs {4x .. 4x+3}; all 8 qt-blocks
    // of a pair share that XCD's L2.
    const int bid = blockIdx.x;
    const int p  = (bid & 7) * 4 + ((bid >> 3) >> 3);   // pair 0..31
    const int qt = (bid >> 3) & 7;                      // 0..7 (256-row tiles)
    const int h = p & 15, b = p >> 4;

    const int sr = t >> 3;              // staging row 0..63
    const int sc = t & 7;               // staging 16B slot

    const unsigned short* Kbase = Kg  + (size_t)(b * SS) * DD + h * DHH;
    const unsigned short* Vbase = Vtg + ((size_t)((b * HH + h) * DHH)) * SS;

    // Q fragments: lane holds Q[q = qt*256 + w*32 + col][d = i*16 + hi*8 + j]
    bf16x8 qa[4];
    {
        const unsigned short* qp =
            Qg + (size_t)(b * SS + qt * 256 + w * 32 + col) * DD + h * DHH + hi * 8;
#pragma unroll
        for (int i = 0; i < 4; ++i) qa[i] = ldfrag(qp + i * 16);
    }

    f32x16 o0 = (f32x16)0.f, o1 = (f32x16)0.f;
    float lsum = 0.f;
    // two-level swizzle keys: f(row) = (row ^ (row>>3)) & 7
    const int xr2 = (col ^ (col >> 3)) & 7;    // read key row col; col+32 -> ^4
    const int wsw = (sr ^ (sr >> 3)) & 7;      // write key for row sr (0..63)

    // two register sets, 2 tiles each (K+V per tile)
    uint4 aK0, aV0, aK1, aV1, bK0, bV0, bK1, bV1;
#define LD2(K0, V0, K1, V1, s0) \
    K0 = *(const uint4*)(Kbase + (size_t)((s0)      + sr) * DD + sc * 8); \
    V0 = *(const uint4*)(Vbase + (size_t)sr * SS + (s0)      + sc * 8); \
    K1 = *(const uint4*)(Kbase + (size_t)((s0) + 64 + sr) * DD + sc * 8); \
    V1 = *(const uint4*)(Vbase + (size_t)sr * SS + (s0) + 64 + sc * 8);

#define ST2(K0, V0, K1, V1, b0, b1) \
    *(uint4*)&Kb[b0][sr][(sc ^ wsw) * 8] = K0; \
    *(uint4*)&Vb[b0][sr][(sc ^ wsw) * 8] = V0; \
    *(uint4*)&Kb[b1][sr][(sc ^ wsw) * 8] = K1; \
    *(uint4*)&Vb[b1][sr][(sc ^ wsw) * 8] = V1;

// one 64-k tile from LDS buffer BUF (compile-time)
#define TILE(BUF)                                                             \
    {                                                                         \
        f32x16 st0 = (f32x16)0.f, st1 = (f32x16)0.f;                          \
        __builtin_amdgcn_s_setprio(1);                                        \
        _Pragma("unroll")                                                     \
        for (int i = 0; i < 4; ++i) {                                         \
            const int sl = (i * 2 + hi) ^ xr2;                                \
            bf16x8 ka0 = ldfrag(&Kb[BUF][col     ][sl * 8]);                  \
            bf16x8 ka1 = ldfrag(&Kb[BUF][col + 32][(sl ^ 4) * 8]);            \
            st0 = __builtin_amdgcn_mfma_f32_32x32x16_bf16(ka0, qa[i], st0, 0, 0, 0); \
            st1 = __builtin_amdgcn_mfma_f32_32x32x16_bf16(ka1, qa[i], st1, 0, 0, 0); \
        }                                                                     \
        __builtin_amdgcn_s_setprio(0);                                        \
        unsigned pkw[4][4];                                                   \
        float ls = 0.f;                                                       \
        _Pragma("unroll")                                                     \
        for (int s = 0; s < 2; ++s) {                                         \
            float pe[8];                                                      \
            _Pragma("unroll")                                                 \
            for (int r = 0; r < 8; ++r) pe[r] = fexp2(st0[8 * s + r]);        \
            ls += ((pe[0] + pe[1]) + (pe[2] + pe[3])) + ((pe[4] + pe[5]) + (pe[6] + pe[7])); \
            pkw[s][0] = pkbf(pe[0], pe[1]); pkw[s][1] = pkbf(pe[2], pe[3]);   \
            pkw[s][2] = pkbf(pe[4], pe[5]); pkw[s][3] = pkbf(pe[6], pe[7]);   \
        }                                                                     \
        _Pragma("unroll")                                                     \
        for (int s = 0; s < 2; ++s) {                                         \
            float pe[8];                                                      \
            _Pragma("unroll")                                                 \
            for (int r = 0; r < 8; ++r) pe[r] = fexp2(st1[8 * s + r]);        \
            ls += ((pe[0] + pe[1]) + (pe[2] + pe[3])) + ((pe[4] + pe[5]) + (pe[6] + pe[7])); \
            pkw[2 + s][0] = pkbf(pe[0], pe[1]); pkw[2 + s][1] = pkbf(pe[2], pe[3]); \
            pkw[2 + s][2] = pkbf(pe[4], pe[5]); pkw[2 + s][3] = pkbf(pe[6], pe[7]); \
        }                                                                     \
        lsum += ls;                                                           \
        __builtin_amdgcn_s_setprio(1);                                        \
        _Pragma("unroll")                                                     \
        for (int c = 0; c < 4; ++c) {                                         \
            unsigned A0 = pkw[c][0], B0 = pkw[c][2];                          \
            unsigned A1 = pkw[c][1], B1 = pkw[c][3];                          \
            plswap(A0, B0); plswap(A1, B1);                                   \
            FragU pf;                                                         \
            pf.u.x = A0; pf.u.y = A1; pf.u.z = B0; pf.u.w = B1;               \
            const int vl = (c * 2 + hi) ^ xr2;                                \
            bf16x8 vb0 = ldfrag(&Vb[BUF][col     ][vl * 8]);                  \
            bf16x8 vb1 = ldfrag(&Vb[BUF][col + 32][(vl ^ 4) * 8]);            \
            o0 = __builtin_amdgcn_mfma_f32_32x32x16_bf16(pf.v, vb0, o0, 0, 0, 0); \
            o1 = __builtin_amdgcn_mfma_f32_32x32x16_bf16(pf.v, vb1, o1, 0, 0, 0); \
        }                                                                     \
        __builtin_amdgcn_s_setprio(0);                                        \
    }

    // prologue: tiles 0,1 -> bufs 0,1 ; tiles 2,3 in regs (set b)
    LD2(aK0, aV0, aK1, aV1, 0)
    ST2(aK0, aV0, aK1, aV1, 0, 1)
    LD2(bK0, bV0, bK1, bV1, 128)
    __syncthreads();

    // 8 iterations x 2 bodies; body = 2 tiles (128 k) + 1 barrier
    for (int tt = 0; tt < SS; tt += 256) {
        // bodyA: compute bufs 0,1 (tiles tt, tt+64); LDa(tt+256,tt+320);
        //        ST set b (tiles tt+128,tt+192) -> bufs 2,3
        if (tt + 256 < SS) { LD2(aK0, aV0, aK1, aV1, tt + 256) }
        TILE(0)
        ST2(bK0, bV0, bK1, bV1, 2, 3)
        TILE(1)
        __syncthreads();
        // bodyB: compute bufs 2,3; LDb(tt+384,tt+448); ST set a -> bufs 0,1
        if (tt + 384 < SS) { LD2(bK0, bV0, bK1, bV1, tt + 384) }
        TILE(2)
        if (tt + 256 < SS) { ST2(aK0, aV0, aK1, aV1, 0, 1) }
        TILE(3)
        if (tt + 256 < SS) __syncthreads();
    }
#undef TILE
#undef LD2
#undef ST2

    // epilogue: l = full-row sum; broadcast 1/l via LDS
    const float lt = lsum + __shfl_xor(lsum, 32);
    if (lane < 32) Lp[w][lane] = lt;
    __syncthreads();

    // rows = crow(reg,hi), cols = lane&31 (+32 for o1)
    const size_t gbase = (size_t)(b * SS + qt * 256 + w * 32) * DD + h * DHH + col;
#pragma unroll
    for (int reg = 0; reg < 16; ++reg) {
        const int rl = (reg & 3) + 8 * (reg >> 2) + 4 * hi;
        const float li = 1.f / Lp[w][rl];
        const size_t g = gbase + (size_t)rl * DD;
        outp[g]      = o0[reg] * li + queries[g];
        outp[g + 32] = o1[reg] * li + queries[g + 32];
    }
}

// ---------------------------------------------------------------------------
extern "C" void kernel_launch(void* const* d_in, const int* in_sizes, int n_in,
                              void* d_out, int out_size, void* d_ws, size_t ws_size,
                              hipStream_t stream) {
    const float* queries = (const float*)d_in[0];
    const float* keys    = (const float*)d_in[1];
    const float* values  = (const float*)d_in[2];
    const float* Wq      = (const float*)d_in[3];
    const float* bq      = (const float*)d_in[4];
    const float* Wk      = (const float*)d_in[5];
    const float* bk      = (const float*)d_in[6];
    const float* Wv      = (const float*)d_in[7];
    const float* bv      = (const float*)d_in[8];
    float* outp = (float*)d_out;

    // scratch: prefer d_ws (54 MB needed); fall back to device globals.
    const size_t need = (6 * N_QKV + 3 * N_W) * sizeof(unsigned short);
    unsigned short *Xp, *Qp, *Kp, *Vtp, *Wtp;
    if (ws_size >= need) {
        Xp  = (unsigned short*)d_ws;
        Qp  = Xp + 3 * N_QKV;
        Kp  = Qp + N_QKV;
        Vtp = Kp + N_QKV;
        Wtp = Vtp + N_QKV;
    } else {
        hipGetSymbolAddress((void**)&Xp,  HIP_SYMBOL(g_X));
        hipGetSymbolAddress((void**)&Qp,  HIP_SYMBOL(g_Q));
        hipGetSymbolAddress((void**)&Kp,  HIP_SYMBOL(g_K));
        hipGetSymbolAddress((void**)&Vtp, HIP_SYMBOL(g_Vt));
        hipGetSymbolAddress((void**)&Wtp, HIP_SYMBOL(g_Wt));
    }

    const dim3 bp(256);
    prep3<<<dim3(4096 + 256, 3), bp, 0, stream>>>(queries, keys, values, Xp,
                                                  Wq, Wk, Wv, Wtp);
    proj3<<<dim3(768), bp, 0, stream>>>(Xp, Wtp, bq, bk, bv, Qp, Kp, Vtp);
    attn11<<<dim3(256), dim3(512), 0, stream>>>(Qp, Kp, Vtp, queries, outp);
}